// Round 5
// baseline (1071.892 us; speedup 1.0000x reference)
//
#include <hip/hip_runtime.h>
#include <math.h>

#define T_TOK 8192
#define DDIM  1024
#define FDIM  4096
#define NEXP  8
#define MT256 72   // max 256-row tiles over all experts

typedef __attribute__((ext_vector_type(8))) short short8;
typedef __attribute__((ext_vector_type(4))) float f32x4;
typedef unsigned short u16;
typedef unsigned int   u32;

typedef const __attribute__((address_space(1))) u32* gp_t;
typedef       __attribute__((address_space(3))) u32* lp_t;

__device__ __forceinline__ void gload16(const void* g, void* l) {
  __builtin_amdgcn_global_load_lds((gp_t)g, (lp_t)l, 16, 0, 0);
}

#define VM4 asm volatile("s_waitcnt vmcnt(4)" ::: "memory")
#define VM3 asm volatile("s_waitcnt vmcnt(3)" ::: "memory")
#define VM0 asm volatile("s_waitcnt vmcnt(0)" ::: "memory")
#define SBAR __builtin_amdgcn_s_barrier()
#define SCHED0 __builtin_amdgcn_sched_barrier(0)

__device__ __forceinline__ u16 f2bf(float f) {
  u32 u = __float_as_uint(f);
  u = u + 0x7FFFu + ((u >> 16) & 1u);
  return (u16)(u >> 16);
}

__device__ __forceinline__ int imin(int a, int b) { return a < b ? a : b; }

// fast gelu (tanh form); |err| vs exact-erf gelu ~1e-3 << 0.0398 threshold
__device__ __forceinline__ float gelu_fast(float v) {
  float u = 0.7978845608f * (v + 0.044715f * v * v * v);
  float t2 = __expf(2.f * u);
  float th = 1.f - 2.f / (t2 + 1.f);
  return 0.5f * v * (1.f + th);
}

// bijective XCD chunking (m204)
__device__ __forceinline__ int xcd_swz(int orig, int nwg) {
  int xcd = orig & 7;
  int q = nwg >> 3, r = nwg & 7;
  int base = (xcd < r) ? xcd * (q + 1) : r * (q + 1) + (xcd - r) * q;
  return base + (orig >> 3);
}

// ---------------- router (+ x->bf16 fused): one wave per token ----------------
__global__ __launch_bounds__(256) void router_kernel(
    const float* __restrict__ x, const float* __restrict__ gw,
    const float* __restrict__ gb, u16* __restrict__ xb,
    int* __restrict__ counts, int* __restrict__ sel, float* __restrict__ wts)
{
  const int t    = blockIdx.x * 4 + (threadIdx.x >> 6);
  const int lane = threadIdx.x & 63;
  const float* xr = x + (size_t)t * DDIM;
  u16* xbr = xb + (size_t)t * DDIM;
  float lg[NEXP];
  #pragma unroll
  for (int e = 0; e < NEXP; e++) lg[e] = 0.f;
  #pragma unroll
  for (int i = 0; i < 4; i++) {
    int d0 = i * 256 + lane * 4;
    float4 v = *(const float4*)(xr + d0);
    ushort4 o;
    o.x = f2bf(v.x); o.y = f2bf(v.y); o.z = f2bf(v.z); o.w = f2bf(v.w);
    *(ushort4*)(xbr + d0) = o;
    const float* g = gw + (size_t)d0 * NEXP;
    #pragma unroll
    for (int e = 0; e < NEXP; e++)
      lg[e] += v.x * g[e] + v.y * g[NEXP + e] + v.z * g[2 * NEXP + e] + v.w * g[3 * NEXP + e];
  }
  #pragma unroll
  for (int off = 32; off > 0; off >>= 1) {
    #pragma unroll
    for (int e = 0; e < NEXP; e++) lg[e] += __shfl_down(lg[e], off);
  }
  if (lane == 0) {
    float v0 = -1e30f, v1 = -1e30f; int s0 = 0, s1 = 0;
    #pragma unroll
    for (int e = 0; e < NEXP; e++) {
      float v = lg[e] + gb[e];
      if (v > v0) { v1 = v0; s1 = s0; v0 = v; s0 = e; }
      else if (v > v1) { v1 = v; s1 = e; }
    }
    float a  = expf(v1 - v0);
    float w0 = 1.f / (1.f + a);
    sel[t * 2] = s0; sel[t * 2 + 1] = s1;
    wts[t * 2] = w0; wts[t * 2 + 1] = 1.f - w0;
    atomicAdd(&counts[s0], 1); atomicAdd(&counts[s1], 1);
  }
}

// ---------------- scan + tile map (256-row tiles) + slot assignment ----------
__global__ __launch_bounds__(256) void scan_assign_kernel(
    const int* __restrict__ counts, const int* __restrict__ sel,
    const float* __restrict__ wts,
    int* __restrict__ offsets, int* __restrict__ map_e, int* __restrict__ map_r,
    int* __restrict__ nT, int* __restrict__ stok, float* __restrict__ swgt)
{
  __shared__ int spos[NEXP];
  if (threadIdx.x == 0) {
    int run = 0, nt = 0;
    for (int e = 0; e < NEXP; e++) {
      offsets[e] = run; spos[e] = run;
      int c = counts[e];
      int ntile = (c + 255) >> 8;
      for (int i = 0; i < ntile; i++) { map_e[nt] = e; map_r[nt] = i * 256; nt++; }
      run += c;
    }
    nT[0] = nt;
  }
  __syncthreads();
  for (int t = threadIdx.x; t < T_TOK; t += 256) {
    #pragma unroll
    for (int k = 0; k < 2; k++) {
      int e = sel[t * 2 + k];
      int p = atomicAdd(&spos[e], 1);
      stok[p] = t; swgt[p] = wts[t * 2 + k];
    }
  }
}

// ---- weight transpose + bf16: in [M][N] f32 -> out [N][M] bf16 ----
__global__ __launch_bounds__(256) void wtrans_kernel(
    const float* __restrict__ in, u16* __restrict__ out, int M, int N)
{
  const int e = blockIdx.z;
  in  += (size_t)e * M * N;
  out += (size_t)e * M * N;
  const int r0 = blockIdx.y * 128;  // M dim
  const int c0 = blockIdx.x * 64;   // N dim
  __shared__ float tile[128][65];
  const int tid = threadIdx.x;
  const int lr = tid >> 4;
  const int lc = (tid & 15) * 4;
  #pragma unroll
  for (int p = 0; p < 8; p++) {
    int r = p * 16 + lr;
    float4 v = *(const float4*)(in + (size_t)(r0 + r) * N + (c0 + lc));
    tile[r][lc] = v.x; tile[r][lc + 1] = v.y; tile[r][lc + 2] = v.z; tile[r][lc + 3] = v.w;
  }
  __syncthreads();
  const int oc = tid >> 4;
  const int om = (tid & 15) * 8;
  #pragma unroll
  for (int p = 0; p < 4; p++) {
    int c = p * 16 + oc;
    short8 o;
    #pragma unroll
    for (int j = 0; j < 8; j++) o[j] = (short)f2bf(tile[om + j][c]);
    *(short8*)(out + (size_t)(c0 + c) * M + (r0 + om)) = o;
  }
}

// ---------------- grouped GEMM1: H = gelu(X@W1 + b1) ----------------
// 256x256 tile, BK=32, 8 waves, 3-deep LDS ring, counted vmcnt (never 0 in loop).
// LDS fragment-major: 16B unit (row,ks) at slot ks*256+row -> conflict-free
// ds_read_b128 (16 lanes read 256B contiguous) and linear gload_lds dest.
__global__ __launch_bounds__(512, 2) void gemm1_kernel(
    const u16* __restrict__ XB, const u16* __restrict__ W1T,
    const float* __restrict__ B1,
    const int* __restrict__ counts, const int* __restrict__ offsets,
    const int* __restrict__ slot_token,
    const int* __restrict__ map_e, const int* __restrict__ map_r,
    const int* __restrict__ nT, u16* __restrict__ H)
{
  __shared__ __align__(16) char lds[3 * 32768];
  const int gid   = xcd_swz(blockIdx.x, gridDim.x);
  const int n_idx = gid / MT256;
  const int t_idx = gid - n_idx * MT256;
  if (t_idx >= nT[0]) return;
  const int e    = map_e[t_idx];
  const int row0 = map_r[t_idx];
  const int cnt  = counts[e];
  const int off  = offsets[e];
  const int n0   = n_idx * 256;

  const int tid = threadIdx.x, wave = tid >> 6, lane = tid & 63;
  const int lr = lane & 15, lq = lane >> 4;
  const int wr = wave >> 2, wc = wave & 3;
  const int wdo = wave * 1024;

  // staging sources (fragment-major: thread t stages units s=tid and s=tid+512)
  const int arow = tid & 255;
  int sidx = imin(off + row0 + arow, 2 * T_TOK - 1);
  int tok = slot_token[sidx]; if ((u32)tok >= T_TOK) tok = 0;
  const char* gA = (const char*)XB + (size_t)tok * 2048 + (tid >> 8) * 16;
  const char* gB = (const char*)W1T + ((size_t)(e * FDIM + n0 + arow)) * 2048 + (tid >> 8) * 16;

  auto stage = [&](int r, int kByte) {
    char* a = lds + r * 32768 + wdo;
    char* b = lds + r * 32768 + 16384 + wdo;
    gload16(gA + kByte, a);
    gload16(gA + kByte + 32, a + 8192);
    gload16(gB + kByte, b);
    gload16(gB + kByte + 32, b + 8192);
  };

  f32x4 acc[8][4] = {};
  auto compute = [&](int r) {
    const u16* A  = (const u16*)(lds + r * 32768);
    const u16* Bp = (const u16*)(lds + r * 32768 + 16384);
    short8 a[8], b[4];
    #pragma unroll
    for (int n = 0; n < 4; n++)
      b[n] = *(const short8*)&Bp[(lq * 256 + wc * 64 + n * 16 + lr) * 8];
    #pragma unroll
    for (int m = 0; m < 8; m++)
      a[m] = *(const short8*)&A[(lq * 256 + wr * 128 + m * 16 + lr) * 8];
    __builtin_amdgcn_s_setprio(1);
    #pragma unroll
    for (int m = 0; m < 8; m++)
      #pragma unroll
      for (int n = 0; n < 4; n++)
        acc[m][n] = __builtin_amdgcn_mfma_f32_16x16x32_bf16(a[m], b[n], acc[m][n], 0, 0, 0);
    __builtin_amdgcn_s_setprio(0);
  };

  // NT = 32 tiles (K = 1024, BK = 32)
  stage(0, 0);
  stage(1, 64);
  VM4; SBAR; SCHED0;
  for (int t = 0; t < 30; t++) {
    stage((t + 2) % 3, (t + 2) * 64);
    compute(t % 3);
    SCHED0; VM4; SBAR; SCHED0;
  }
  compute(0);   // tile 30 (ring 0)
  SCHED0; VM0; SBAR; SCHED0;
  compute(1);   // tile 31 (ring 1)

  // epilogue: gelu + store bf16
  #pragma unroll
  for (int m = 0; m < 8; m++) {
    int rloc = wr * 128 + m * 16 + lq * 4;
    #pragma unroll
    for (int j = 0; j < 4; j++) {
      int r = rloc + j;
      if (row0 + r < cnt) {
        u16* Hrow = H + (size_t)(off + row0 + r) * FDIM;
        #pragma unroll
        for (int n = 0; n < 4; n++) {
          int col = n0 + wc * 64 + n * 16 + lr;
          float v = acc[m][n][j] + B1[e * FDIM + col];
          Hrow[col] = f2bf(gelu_fast(v));
        }
      }
    }
  }
}

// ---------------- grouped GEMM2 + fused combine ----------------
// 256x128 tile, BK=32, split-K=2 (each split K=2048 elems = 64 tiles),
// 8 waves (4M x 2N), 3-deep ring, counted vmcnt.
// out[tok] += wgt * (H@W2 + b2) via f32 atomics.
__global__ __launch_bounds__(512, 2) void gemm2_kernel(
    const u16* __restrict__ H, const u16* __restrict__ W2T,
    const float* __restrict__ B2,
    const int* __restrict__ counts, const int* __restrict__ offsets,
    const int* __restrict__ slot_token, const float* __restrict__ slot_weight,
    const int* __restrict__ map_e, const int* __restrict__ map_r,
    const int* __restrict__ nT, float* __restrict__ out)
{
  __shared__ __align__(16) char lds[3 * 24576];
  const int gid   = xcd_swz(blockIdx.x, gridDim.x);
  const int sp    = gid / (8 * MT256);
  const int rem   = gid - sp * 8 * MT256;
  const int n_idx = rem / MT256;
  const int t_idx = rem - n_idx * MT256;
  if (t_idx >= nT[0]) return;
  const int e    = map_e[t_idx];
  const int row0 = map_r[t_idx];
  const int cnt  = counts[e];
  const int off  = offsets[e];
  const int n0   = n_idx * 128;
  const int kbase = sp * 4096; // byte offset: split sp covers elems [sp*2048, sp*2048+2048)

  const int tid = threadIdx.x, wave = tid >> 6, lane = tid & 63;
  const int lr = lane & 15, lq = lane >> 4;
  const int wr = wave >> 1, wc = wave & 1;
  const int wdo = wave * 1024;

  const int arow = tid & 255;
  int sidx = imin(off + row0 + arow, 2 * T_TOK - 1);
  const char* gA = (const char*)H + (size_t)sidx * 8192 + kbase + (tid >> 8) * 16;
  const int brow = tid & 127;
  const char* gB = (const char*)W2T + ((size_t)(e * DDIM + n0 + brow)) * 8192 + kbase + (tid >> 7) * 16;

  auto stage = [&](int r, int kByte) {
    char* a = lds + r * 24576 + wdo;
    char* b = lds + r * 24576 + 16384 + wdo;
    gload16(gA + kByte, a);
    gload16(gA + kByte + 32, a + 8192);
    gload16(gB + kByte, b);
  };

  f32x4 acc[4][4] = {};
  auto compute = [&](int r) {
    const u16* A  = (const u16*)(lds + r * 24576);
    const u16* Bp = (const u16*)(lds + r * 24576 + 16384);
    short8 a[4], b[4];
    #pragma unroll
    for (int n = 0; n < 4; n++)
      b[n] = *(const short8*)&Bp[(lq * 128 + wc * 64 + n * 16 + lr) * 8];
    #pragma unroll
    for (int m = 0; m < 4; m++)
      a[m] = *(const short8*)&A[(lq * 256 + wr * 64 + m * 16 + lr) * 8];
    __builtin_amdgcn_s_setprio(1);
    #pragma unroll
    for (int m = 0; m < 4; m++)
      #pragma unroll
      for (int n = 0; n < 4; n++)
        acc[m][n] = __builtin_amdgcn_mfma_f32_16x16x32_bf16(a[m], b[n], acc[m][n], 0, 0, 0);
    __builtin_amdgcn_s_setprio(0);
  };

  // NT = 64 tiles (split K = 2048 elems, BK = 32)
  stage(0, 0);
  stage(1, 64);
  VM3; SBAR; SCHED0;
  for (int t = 0; t < 62; t++) {
    stage((t + 2) % 3, (t + 2) * 64);
    compute(t % 3);
    SCHED0; VM3; SBAR; SCHED0;
  }
  compute(2);   // tile 62 (ring 2)
  SCHED0; VM0; SBAR; SCHED0;
  compute(0);   // tile 63 (ring 0)

  #pragma unroll
  for (int m = 0; m < 4; m++) {
    int rloc = wr * 64 + m * 16 + lq * 4;
    #pragma unroll
    for (int j = 0; j < 4; j++) {
      int r = rloc + j;
      if (row0 + r >= cnt) continue;
      int s = off + row0 + r;
      int tok = slot_token[s];
      float wgt = slot_weight[s];
      #pragma unroll
      for (int n = 0; n < 4; n++) {
        int col = n0 + wc * 64 + n * 16 + lr;
        float v = acc[m][n][j];
        if (sp == 0) v += B2[e * DDIM + col];
        atomicAdd(&out[(size_t)tok * DDIM + col], wgt * v);
      }
    }
  }
}

extern "C" void kernel_launch(void* const* d_in, const int* in_sizes, int n_in,
                              void* d_out, int out_size, void* d_ws, size_t ws_size,
                              hipStream_t stream)
{
  (void)in_sizes; (void)n_in; (void)ws_size;
  const float* x  = (const float*)d_in[0];
  const float* gw = (const float*)d_in[1];
  const float* gb = (const float*)d_in[2];
  const float* w1 = (const float*)d_in[3];
  const float* b1 = (const float*)d_in[4];
  const float* w2 = (const float*)d_in[5];
  const float* b2 = (const float*)d_in[6];

  char* ws = (char*)d_ws;
  int*   counts = (int*)(ws + 0);
  int*   offp   = (int*)(ws + 64);
  int*   nT     = (int*)(ws + 128);
  int*   map_e  = (int*)(ws + 256);
  int*   map_r  = (int*)(ws + 1024);

  size_t p = 2048;
  int*   sel   = (int*)(ws + p);   p += (size_t)T_TOK * 2 * 4;
  float* wts   = (float*)(ws + p); p += (size_t)T_TOK * 2 * 4;
  int*   stok  = (int*)(ws + p);   p += (size_t)(2 * T_TOK + 512) * 4;
  float* swgt  = (float*)(ws + p); p += (size_t)(2 * T_TOK + 512) * 4;
  p = (p + 1048575) & ~(size_t)1048575;
  u16*   xb    = (u16*)(ws + p);   p += (size_t)T_TOK * DDIM * 2;
  u16*   w1t   = (u16*)(ws + p);   p += (size_t)NEXP * DDIM * FDIM * 2;
  u16*   w2t   = (u16*)(ws + p);   p += (size_t)NEXP * DDIM * FDIM * 2;
  u16*   Hbuf  = (u16*)(ws + p);

  hipMemsetAsync(ws, 0, 256, stream);
  hipMemsetAsync(d_out, 0, (size_t)out_size * sizeof(float), stream);
  router_kernel<<<T_TOK / 4, 256, 0, stream>>>(x, gw, gb, xb, counts, sel, wts);
  scan_assign_kernel<<<1, 256, 0, stream>>>(counts, sel, wts, offp, map_e, map_r, nT, stok, swgt);
  // W2 first so w1t is cache-warm when gemm1 starts
  wtrans_kernel<<<dim3(DDIM / 64, FDIM / 128, NEXP), 256, 0, stream>>>(w2, w2t, FDIM, DDIM);
  wtrans_kernel<<<dim3(FDIM / 64, DDIM / 128, NEXP), 256, 0, stream>>>(w1, w1t, DDIM, FDIM);

  gemm1_kernel<<<(FDIM / 256) * MT256, 512, 0, stream>>>(
      xb, w1t, b1, counts, offp, stok, map_e, map_r, nT, Hbuf);
  gemm2_kernel<<<2 * (DDIM / 128) * MT256, 512, 0, stream>>>(
      Hbuf, w2t, b2, counts, offp, stok, swgt, map_e, map_r, nT, (float*)d_out);
}

// Round 7
// 1040.368 us; speedup vs baseline: 1.0303x; 1.0303x over previous
//
#include <hip/hip_runtime.h>
#include <math.h>

#define T_TOK 8192
#define DDIM  1024
#define FDIM  4096
#define NEXP  8
#define MT256 72   // max 256-row tiles over all experts
#define NSLOT (2 * T_TOK)

typedef __attribute__((ext_vector_type(8))) short short8;
typedef __attribute__((ext_vector_type(4))) float f32x4;
typedef unsigned short u16;
typedef unsigned int   u32;

typedef const __attribute__((address_space(1))) u32* gp_t;
typedef       __attribute__((address_space(3))) u32* lp_t;

__device__ __forceinline__ void gload16(const void* g, void* l) {
  __builtin_amdgcn_global_load_lds((gp_t)g, (lp_t)l, 16, 0, 0);
}

#define VM8 asm volatile("s_waitcnt vmcnt(8)" ::: "memory")
#define VM4 asm volatile("s_waitcnt vmcnt(4)" ::: "memory")
#define VM0 asm volatile("s_waitcnt vmcnt(0)" ::: "memory")
#define SBAR __builtin_amdgcn_s_barrier()
#define SCHED0 __builtin_amdgcn_sched_barrier(0)

__device__ __forceinline__ u16 f2bf(float f) {
  u32 u = __float_as_uint(f);
  u = u + 0x7FFFu + ((u >> 16) & 1u);
  return (u16)(u >> 16);
}

__device__ __forceinline__ int imin(int a, int b) { return a < b ? a : b; }

// fast gelu (tanh form); |err| vs exact-erf gelu ~1e-3 << 0.0398 threshold
__device__ __forceinline__ float gelu_fast(float v) {
  float u = 0.7978845608f * (v + 0.044715f * v * v * v);
  float t2 = __expf(2.f * u);
  float th = 1.f - 2.f / (t2 + 1.f);
  return 0.5f * v * (1.f + th);
}

// bijective XCD chunking (m204)
__device__ __forceinline__ int xcd_swz(int orig, int nwg) {
  int xcd = orig & 7;
  int q = nwg >> 3, r = nwg & 7;
  int base = (xcd < r) ? xcd * (q + 1) : r * (q + 1) + (xcd - r) * q;
  return base + (orig >> 3);
}

// ---------------- router (+ x->bf16 fused): one wave per token ----------------
__global__ __launch_bounds__(256) void router_kernel(
    const float* __restrict__ x, const float* __restrict__ gw,
    const float* __restrict__ gb, u16* __restrict__ xb,
    int* __restrict__ counts, int* __restrict__ sel, float* __restrict__ wts)
{
  const int t    = blockIdx.x * 4 + (threadIdx.x >> 6);
  const int lane = threadIdx.x & 63;
  const float* xr = x + (size_t)t * DDIM;
  u16* xbr = xb + (size_t)t * DDIM;
  float lg[NEXP];
  #pragma unroll
  for (int e = 0; e < NEXP; e++) lg[e] = 0.f;
  #pragma unroll
  for (int i = 0; i < 4; i++) {
    int d0 = i * 256 + lane * 4;
    float4 v = *(const float4*)(xr + d0);
    ushort4 o;
    o.x = f2bf(v.x); o.y = f2bf(v.y); o.z = f2bf(v.z); o.w = f2bf(v.w);
    *(ushort4*)(xbr + d0) = o;
    const float* g = gw + (size_t)d0 * NEXP;
    #pragma unroll
    for (int e = 0; e < NEXP; e++)
      lg[e] += v.x * g[e] + v.y * g[NEXP + e] + v.z * g[2 * NEXP + e] + v.w * g[3 * NEXP + e];
  }
  #pragma unroll
  for (int off = 32; off > 0; off >>= 1) {
    #pragma unroll
    for (int e = 0; e < NEXP; e++) lg[e] += __shfl_down(lg[e], off);
  }
  if (lane == 0) {
    float v0 = -1e30f, v1 = -1e30f; int s0 = 0, s1 = 0;
    #pragma unroll
    for (int e = 0; e < NEXP; e++) {
      float v = lg[e] + gb[e];
      if (v > v0) { v1 = v0; s1 = s0; v0 = v; s0 = e; }
      else if (v > v1) { v1 = v; s1 = e; }
    }
    float a  = expf(v1 - v0);
    float w0 = 1.f / (1.f + a);
    sel[t * 2] = s0; sel[t * 2 + 1] = s1;
    wts[t * 2] = w0; wts[t * 2 + 1] = 1.f - w0;
    atomicAdd(&counts[s0], 1); atomicAdd(&counts[s1], 1);
  }
}

// ---------------- scan + tile map (256-row tiles) + slot assignment ----------
__global__ __launch_bounds__(256) void scan_assign_kernel(
    const int* __restrict__ counts, const int* __restrict__ sel,
    const float* __restrict__ wts,
    int* __restrict__ offsets, int* __restrict__ map_e, int* __restrict__ map_r,
    int* __restrict__ nT, int* __restrict__ stok, float* __restrict__ swgt)
{
  __shared__ int spos[NEXP];
  if (threadIdx.x == 0) {
    int run = 0, nt = 0;
    for (int e = 0; e < NEXP; e++) {
      offsets[e] = run; spos[e] = run;
      int c = counts[e];
      int ntile = (c + 255) >> 8;
      for (int i = 0; i < ntile; i++) { map_e[nt] = e; map_r[nt] = i * 256; nt++; }
      run += c;
    }
    nT[0] = nt;
  }
  __syncthreads();
  for (int t = threadIdx.x; t < T_TOK; t += 256) {
    #pragma unroll
    for (int k = 0; k < 2; k++) {
      int e = sel[t * 2 + k];
      int p = atomicAdd(&spos[e], 1);
      stok[p] = t; swgt[p] = wts[t * 2 + k];
    }
  }
}

// ---------------- gather X rows into slot order: Xg[s] = xb[stok[s]] --------
__global__ __launch_bounds__(256) void xgather_kernel(
    const u16* __restrict__ xb, const int* __restrict__ stok,
    u16* __restrict__ Xg)
{
  const int s = blockIdx.x * 2 + (threadIdx.x >> 7);
  const int u = threadIdx.x & 127;
  int tok = stok[s]; if ((u32)tok >= T_TOK) tok = 0;
  const uint4* src = (const uint4*)(xb + (size_t)tok * DDIM);
  uint4* dst = (uint4*)(Xg + (size_t)s * DDIM);
  dst[u] = src[u];
}

// ---- weight transpose + bf16: in [M][N] f32 -> out [N][M] bf16 ----
__global__ __launch_bounds__(256) void wtrans_kernel(
    const float* __restrict__ in, u16* __restrict__ out, int M, int N)
{
  const int e = blockIdx.z;
  in  += (size_t)e * M * N;
  out += (size_t)e * M * N;
  const int r0 = blockIdx.y * 128;  // M dim
  const int c0 = blockIdx.x * 64;   // N dim
  __shared__ float tile[128][65];
  const int tid = threadIdx.x;
  const int lr = tid >> 4;
  const int lc = (tid & 15) * 4;
  #pragma unroll
  for (int p = 0; p < 8; p++) {
    int r = p * 16 + lr;
    float4 v = *(const float4*)(in + (size_t)(r0 + r) * N + (c0 + lc));
    tile[r][lc] = v.x; tile[r][lc + 1] = v.y; tile[r][lc + 2] = v.z; tile[r][lc + 3] = v.w;
  }
  __syncthreads();
  const int oc = tid >> 4;
  const int om = (tid & 15) * 8;
  #pragma unroll
  for (int p = 0; p < 4; p++) {
    int c = p * 16 + oc;
    short8 o;
    #pragma unroll
    for (int j = 0; j < 8; j++) o[j] = (short)f2bf(tile[om + j][c]);
    *(short8*)(out + (size_t)(c0 + c) * M + (r0 + om)) = o;
  }
}

// ---------------- grouped GEMM1: H = gelu(Xg@W1 + b1) ----------------
// 256x256, BK=32, 8 waves (2Mx4N), ring-4 LDS (128KB), counted vmcnt lead-3.
// Fragment-major LDS (R5: 0 bank conflicts). R5-proven explicit VM+SBAR sync.
__global__ __launch_bounds__(512, 2) void gemm1_kernel(
    const u16* __restrict__ Xg, const u16* __restrict__ W1T,
    const float* __restrict__ B1,
    const int* __restrict__ counts, const int* __restrict__ offsets,
    const int* __restrict__ map_e, const int* __restrict__ map_r,
    const int* __restrict__ nT, u16* __restrict__ H)
{
  __shared__ __align__(16) char lds[4 * 32768];
  const int gid   = xcd_swz(blockIdx.x, gridDim.x);
  const int n_idx = gid / MT256;
  const int t_idx = gid - n_idx * MT256;
  if (t_idx >= nT[0]) return;
  const int e    = map_e[t_idx];
  const int row0 = map_r[t_idx];
  const int cnt  = counts[e];
  const int off  = offsets[e];
  const int n0   = n_idx * 256;

  const int tid = threadIdx.x, wave = tid >> 6, lane = tid & 63;
  const int lr = lane & 15, lq = lane >> 4;
  const int wr = wave >> 2, wc = wave & 3;   // 2M x 4N

  const int arow = tid & 255;
  const int q0   = tid >> 8;
  int aidx = imin(off + row0 + arow, NSLOT - 1);
  const char* gA = (const char*)Xg + (size_t)aidx * 2048 + q0 * 16;
  const char* gB = (const char*)W1T + ((size_t)(e * FDIM + n0 + arow)) * 2048 + q0 * 16;

  auto stage = [&](int buf, int kByte) {
    char* a = lds + buf * 32768 + tid * 16;
    char* b = a + 16384;
    gload16(gA + kByte, a);
    gload16(gA + kByte + 32, a + 8192);
    gload16(gB + kByte, b);
    gload16(gB + kByte + 32, b + 8192);
  };

  f32x4 acc[8][4] = {};
  auto compute = [&](int buf) {
    const u16* A  = (const u16*)(lds + buf * 32768);
    const u16* Bp = (const u16*)(lds + buf * 32768 + 16384);
    short8 a[8], b[4];
    #pragma unroll
    for (int n = 0; n < 4; n++)
      b[n] = *(const short8*)&Bp[(lq * 256 + wc * 64 + n * 16 + lr) * 8];
    #pragma unroll
    for (int m = 0; m < 8; m++)
      a[m] = *(const short8*)&A[(lq * 256 + wr * 128 + m * 16 + lr) * 8];
    __builtin_amdgcn_s_setprio(1);
    #pragma unroll
    for (int m = 0; m < 8; m++)
      #pragma unroll
      for (int n = 0; n < 4; n++)
        acc[m][n] = __builtin_amdgcn_mfma_f32_16x16x32_bf16(a[m], b[n], acc[m][n], 0, 0, 0);
    __builtin_amdgcn_s_setprio(0);
  };

  // NT = 32 K-steps (K=1024, BK=32); ring-4, lead-3, one barrier per step.
  stage(0, 0); stage(1, 64); stage(2, 128);
  VM8; SCHED0; SBAR; SCHED0;
  #pragma unroll 1
  for (int t = 0; t < 32; t++) {
    if (t + 3 < 32) stage((t + 3) & 3, (t + 3) * 64);
    compute(t & 3);
    SCHED0;
    if (t + 3 < 32)      { VM8; }
    else if (t + 3 == 32){ VM4; }
    else if (t + 2 == 32){ VM0; }
    SCHED0; SBAR; SCHED0;
  }

  // epilogue: gelu + store bf16
  #pragma unroll
  for (int m = 0; m < 8; m++) {
    int rloc = wr * 128 + m * 16 + lq * 4;
    #pragma unroll
    for (int j = 0; j < 4; j++) {
      int r = rloc + j;
      if (row0 + r < cnt) {
        u16* Hrow = H + (size_t)(off + row0 + r) * FDIM;
        #pragma unroll
        for (int n = 0; n < 4; n++) {
          int col = n0 + wc * 64 + n * 16 + lr;
          float v = acc[m][n][j] + B1[e * FDIM + col];
          Hrow[col] = f2bf(gelu_fast(v));
        }
      }
    }
  }
}

// ---------------- grouped GEMM2 + fused combine ----------------
// 256x256, BK=32, split-K=2 (64 steps each), ring-4, counted vmcnt lead-3.
// out[tok] += wgt * (H@W2 + b2) via f32 atomics.
__global__ __launch_bounds__(512, 2) void gemm2_kernel(
    const u16* __restrict__ H, const u16* __restrict__ W2T,
    const float* __restrict__ B2,
    const int* __restrict__ counts, const int* __restrict__ offsets,
    const int* __restrict__ slot_token, const float* __restrict__ slot_weight,
    const int* __restrict__ map_e, const int* __restrict__ map_r,
    const int* __restrict__ nT, float* __restrict__ out)
{
  __shared__ __align__(16) char lds[4 * 32768];
  const int gid   = xcd_swz(blockIdx.x, gridDim.x);
  const int sp    = gid / (4 * MT256);
  const int rem   = gid - sp * 4 * MT256;
  const int n_idx = rem / MT256;
  const int t_idx = rem - n_idx * MT256;
  if (t_idx >= nT[0]) return;
  const int e    = map_e[t_idx];
  const int row0 = map_r[t_idx];
  const int cnt  = counts[e];
  const int off  = offsets[e];
  const int n0   = n_idx * 256;
  const int kbase = sp * 4096;  // bytes: split sp covers k elems [sp*2048, +2048)

  const int tid = threadIdx.x, wave = tid >> 6, lane = tid & 63;
  const int lr = lane & 15, lq = lane >> 4;
  const int wr = wave >> 2, wc = wave & 3;   // 2M x 4N

  const int arow = tid & 255;
  const int q0   = tid >> 8;
  int sidx = imin(off + row0 + arow, NSLOT - 1);
  const char* gA = (const char*)H + (size_t)sidx * 8192 + kbase + q0 * 16;
  const char* gB = (const char*)W2T + ((size_t)(e * DDIM + n0 + arow)) * 8192 + kbase + q0 * 16;

  auto stage = [&](int buf, int kByte) {
    char* a = lds + buf * 32768 + tid * 16;
    char* b = a + 16384;
    gload16(gA + kByte, a);
    gload16(gA + kByte + 32, a + 8192);
    gload16(gB + kByte, b);
    gload16(gB + kByte + 32, b + 8192);
  };

  f32x4 acc[8][4] = {};
  auto compute = [&](int buf) {
    const u16* A  = (const u16*)(lds + buf * 32768);
    const u16* Bp = (const u16*)(lds + buf * 32768 + 16384);
    short8 a[8], b[4];
    #pragma unroll
    for (int n = 0; n < 4; n++)
      b[n] = *(const short8*)&Bp[(lq * 256 + wc * 64 + n * 16 + lr) * 8];
    #pragma unroll
    for (int m = 0; m < 8; m++)
      a[m] = *(const short8*)&A[(lq * 256 + wr * 128 + m * 16 + lr) * 8];
    __builtin_amdgcn_s_setprio(1);
    #pragma unroll
    for (int m = 0; m < 8; m++)
      #pragma unroll
      for (int n = 0; n < 4; n++)
        acc[m][n] = __builtin_amdgcn_mfma_f32_16x16x32_bf16(a[m], b[n], acc[m][n], 0, 0, 0);
    __builtin_amdgcn_s_setprio(0);
  };

  // NT = 64 K-steps per split (K=2048, BK=32)
  stage(0, 0); stage(1, 64); stage(2, 128);
  VM8; SCHED0; SBAR; SCHED0;
  #pragma unroll 1
  for (int t = 0; t < 64; t++) {
    if (t + 3 < 64) stage((t + 3) & 3, (t + 3) * 64);
    compute(t & 3);
    SCHED0;
    if (t + 3 < 64)      { VM8; }
    else if (t + 3 == 64){ VM4; }
    else if (t + 2 == 64){ VM0; }
    SCHED0; SBAR; SCHED0;
  }

  #pragma unroll
  for (int m = 0; m < 8; m++) {
    int rloc = wr * 128 + m * 16 + lq * 4;
    #pragma unroll
    for (int j = 0; j < 4; j++) {
      int r = rloc + j;
      if (row0 + r >= cnt) continue;
      int s = off + row0 + r;
      int tok = slot_token[s];
      float wgt = slot_weight[s];
      #pragma unroll
      for (int n = 0; n < 4; n++) {
        int col = n0 + wc * 64 + n * 16 + lr;
        float v = acc[m][n][j];
        if (sp == 0) v += B2[e * DDIM + col];
        atomicAdd(&out[(size_t)tok * DDIM + col], wgt * v);
      }
    }
  }
}

extern "C" void kernel_launch(void* const* d_in, const int* in_sizes, int n_in,
                              void* d_out, int out_size, void* d_ws, size_t ws_size,
                              hipStream_t stream)
{
  (void)in_sizes; (void)n_in; (void)ws_size;
  const float* x  = (const float*)d_in[0];
  const float* gw = (const float*)d_in[1];
  const float* gb = (const float*)d_in[2];
  const float* w1 = (const float*)d_in[3];
  const float* b1 = (const float*)d_in[4];
  const float* w2 = (const float*)d_in[5];
  const float* b2 = (const float*)d_in[6];

  char* ws = (char*)d_ws;
  int*   counts = (int*)(ws + 0);
  int*   offp   = (int*)(ws + 64);
  int*   nT     = (int*)(ws + 128);
  int*   map_e  = (int*)(ws + 256);
  int*   map_r  = (int*)(ws + 1024);

  size_t p = 2048;
  int*   sel   = (int*)(ws + p);   p += (size_t)T_TOK * 2 * 4;
  float* wts   = (float*)(ws + p); p += (size_t)T_TOK * 2 * 4;
  int*   stok  = (int*)(ws + p);   p += (size_t)NSLOT * 4;
  float* swgt  = (float*)(ws + p); p += (size_t)NSLOT * 4;
  p = (p + 1048575) & ~(size_t)1048575;
  u16*   xb    = (u16*)(ws + p);   p += (size_t)T_TOK * DDIM * 2;
  u16*   Xg    = (u16*)(ws + p);   p += (size_t)NSLOT * DDIM * 2;
  u16*   w1t   = (u16*)(ws + p);   p += (size_t)NEXP * DDIM * FDIM * 2;
  u16*   w2t   = (u16*)(ws + p);   p += (size_t)NEXP * DDIM * FDIM * 2;
  u16*   Hbuf  = (u16*)(ws + p);   // NSLOT rows x FDIM bf16 (128 MB)

  hipMemsetAsync(ws, 0, 256, stream);
  hipMemsetAsync(d_out, 0, (size_t)out_size * sizeof(float), stream);
  router_kernel<<<T_TOK / 4, 256, 0, stream>>>(x, gw, gb, xb, counts, sel, wts);
  scan_assign_kernel<<<1, 256, 0, stream>>>(counts, sel, wts, offp, map_e, map_r, nT, stok, swgt);
  xgather_kernel<<<NSLOT / 2, 256, 0, stream>>>(xb, stok, Xg);
  // W2 first so w1t is cache-warm when gemm1 starts
  wtrans_kernel<<<dim3(DDIM / 64, FDIM / 128, NEXP), 256, 0, stream>>>(w2, w2t, FDIM, DDIM);
  wtrans_kernel<<<dim3(FDIM / 64, DDIM / 128, NEXP), 256, 0, stream>>>(w1, w1t, DDIM, FDIM);

  gemm1_kernel<<<(FDIM / 256) * MT256, 512, 0, stream>>>(
      Xg, w1t, b1, counts, offp, map_e, map_r, nT, Hbuf);
  gemm2_kernel<<<2 * (DDIM / 256) * MT256, 512, 0, stream>>>(
      Hbuf, w2t, b2, counts, offp, stok, swgt, map_e, map_r, nT, (float*)d_out);
}

// Round 8
// 858.500 us; speedup vs baseline: 1.2486x; 1.2118x over previous
//
#include <hip/hip_runtime.h>
#include <math.h>

#define T_TOK 8192
#define DDIM  1024
#define FDIM  4096
#define NEXP  8
#define MT256 72   // max 256-row tiles over all experts
#define NSLOT (2 * T_TOK)

typedef __attribute__((ext_vector_type(8))) short short8;
typedef __attribute__((ext_vector_type(4))) float f32x4;
typedef unsigned short u16;
typedef unsigned int   u32;

typedef const __attribute__((address_space(1))) u32* gp_t;
typedef       __attribute__((address_space(3))) u32* lp_t;

__device__ __forceinline__ void gload16(const void* g, void* l) {
  __builtin_amdgcn_global_load_lds((gp_t)g, (lp_t)l, 16, 0, 0);
}

#define VM0 asm volatile("s_waitcnt vmcnt(0)" ::: "memory")
#define SBAR __builtin_amdgcn_s_barrier()
#define SCHED0 __builtin_amdgcn_sched_barrier(0)

__device__ __forceinline__ u16 f2bf(float f) {
  u32 u = __float_as_uint(f);
  u = u + 0x7FFFu + ((u >> 16) & 1u);
  return (u16)(u >> 16);
}

__device__ __forceinline__ int imin(int a, int b) { return a < b ? a : b; }

// fast gelu (tanh form); |err| vs exact-erf gelu ~1e-3 << 0.0398 threshold
__device__ __forceinline__ float gelu_fast(float v) {
  float u = 0.7978845608f * (v + 0.044715f * v * v * v);
  float t2 = __expf(2.f * u);
  float th = 1.f - 2.f / (t2 + 1.f);
  return 0.5f * v * (1.f + th);
}

// bijective XCD chunking (m204)
__device__ __forceinline__ int xcd_swz(int orig, int nwg) {
  int xcd = orig & 7;
  int q = nwg >> 3, r = nwg & 7;
  int base = (xcd < r) ? xcd * (q + 1) : r * (q + 1) + (xcd - r) * q;
  return base + (orig >> 3);
}

// ---------------- router (+ x->bf16 fused): one wave per token ----------------
__global__ __launch_bounds__(256) void router_kernel(
    const float* __restrict__ x, const float* __restrict__ gw,
    const float* __restrict__ gb, u16* __restrict__ xb,
    int* __restrict__ counts, int* __restrict__ sel, float* __restrict__ wts)
{
  const int t    = blockIdx.x * 4 + (threadIdx.x >> 6);
  const int lane = threadIdx.x & 63;
  const float* xr = x + (size_t)t * DDIM;
  u16* xbr = xb + (size_t)t * DDIM;
  float lg[NEXP];
  #pragma unroll
  for (int e = 0; e < NEXP; e++) lg[e] = 0.f;
  #pragma unroll
  for (int i = 0; i < 4; i++) {
    int d0 = i * 256 + lane * 4;
    float4 v = *(const float4*)(xr + d0);
    ushort4 o;
    o.x = f2bf(v.x); o.y = f2bf(v.y); o.z = f2bf(v.z); o.w = f2bf(v.w);
    *(ushort4*)(xbr + d0) = o;
    const float* g = gw + (size_t)d0 * NEXP;
    #pragma unroll
    for (int e = 0; e < NEXP; e++)
      lg[e] += v.x * g[e] + v.y * g[NEXP + e] + v.z * g[2 * NEXP + e] + v.w * g[3 * NEXP + e];
  }
  #pragma unroll
  for (int off = 32; off > 0; off >>= 1) {
    #pragma unroll
    for (int e = 0; e < NEXP; e++) lg[e] += __shfl_down(lg[e], off);
  }
  if (lane == 0) {
    float v0 = -1e30f, v1 = -1e30f; int s0 = 0, s1 = 0;
    #pragma unroll
    for (int e = 0; e < NEXP; e++) {
      float v = lg[e] + gb[e];
      if (v > v0) { v1 = v0; s1 = s0; v0 = v; s0 = e; }
      else if (v > v1) { v1 = v; s1 = e; }
    }
    float a  = expf(v1 - v0);
    float w0 = 1.f / (1.f + a);
    sel[t * 2] = s0; sel[t * 2 + 1] = s1;
    wts[t * 2] = w0; wts[t * 2 + 1] = 1.f - w0;
    atomicAdd(&counts[s0], 1); atomicAdd(&counts[s1], 1);
  }
}

// ---------------- scan + tile map (256-row tiles) + slot assignment ----------
__global__ __launch_bounds__(256) void scan_assign_kernel(
    const int* __restrict__ counts, const int* __restrict__ sel,
    const float* __restrict__ wts,
    int* __restrict__ offsets, int* __restrict__ map_e, int* __restrict__ map_r,
    int* __restrict__ nT, int* __restrict__ stok, float* __restrict__ swgt)
{
  __shared__ int spos[NEXP];
  if (threadIdx.x == 0) {
    int run = 0, nt = 0;
    for (int e = 0; e < NEXP; e++) {
      offsets[e] = run; spos[e] = run;
      int c = counts[e];
      int ntile = (c + 255) >> 8;
      for (int i = 0; i < ntile; i++) { map_e[nt] = e; map_r[nt] = i * 256; nt++; }
      run += c;
    }
    nT[0] = nt;
  }
  __syncthreads();
  for (int t = threadIdx.x; t < T_TOK; t += 256) {
    #pragma unroll
    for (int k = 0; k < 2; k++) {
      int e = sel[t * 2 + k];
      int p = atomicAdd(&spos[e], 1);
      stok[p] = t; swgt[p] = wts[t * 2 + k];
    }
  }
}

// ---------------- gather X rows into slot order: Xg[s] = xb[stok[s]] --------
__global__ __launch_bounds__(256) void xgather_kernel(
    const u16* __restrict__ xb, const int* __restrict__ stok,
    u16* __restrict__ Xg)
{
  const int s = blockIdx.x * 2 + (threadIdx.x >> 7);
  const int u = threadIdx.x & 127;
  int tok = stok[s]; if ((u32)tok >= T_TOK) tok = 0;
  const uint4* src = (const uint4*)(xb + (size_t)tok * DDIM);
  uint4* dst = (uint4*)(Xg + (size_t)s * DDIM);
  dst[u] = src[u];
}

// ---- weight transpose + bf16: in [M][N] f32 -> out [N][M] bf16 ----
__global__ __launch_bounds__(256) void wtrans_kernel(
    const float* __restrict__ in, u16* __restrict__ out, int M, int N)
{
  const int e = blockIdx.z;
  in  += (size_t)e * M * N;
  out += (size_t)e * M * N;
  const int r0 = blockIdx.y * 128;  // M dim
  const int c0 = blockIdx.x * 64;   // N dim
  __shared__ float tile[128][65];
  const int tid = threadIdx.x;
  const int lr = tid >> 4;
  const int lc = (tid & 15) * 4;
  #pragma unroll
  for (int p = 0; p < 8; p++) {
    int r = p * 16 + lr;
    float4 v = *(const float4*)(in + (size_t)(r0 + r) * N + (c0 + lc));
    tile[r][lc] = v.x; tile[r][lc + 1] = v.y; tile[r][lc + 2] = v.z; tile[r][lc + 3] = v.w;
  }
  __syncthreads();
  const int oc = tid >> 4;
  const int om = (tid & 15) * 8;
  #pragma unroll
  for (int p = 0; p < 4; p++) {
    int c = p * 16 + oc;
    short8 o;
    #pragma unroll
    for (int j = 0; j < 8; j++) o[j] = (short)f2bf(tile[om + j][c]);
    *(short8*)(out + (size_t)(c0 + c) * M + (r0 + om)) = o;
  }
}

// ---------------- grouped GEMM1: H = gelu(Xg@W1 + b1) ----------------
// 256x256, BK=64, 8 waves (2Mx4N), dbuf 128KB, 2-phase (m248 recipe):
// stage(next) -> ds_read+MFMA(cur) -> vmcnt(0) -> s_barrier, once per K-step.
// LDS: row-major [256][128B] rows; XOR-unit swizzle (unit ^= row&7) applied via
// pre-swizzled GLOBAL source (rule #21) with linear gload_lds dest. Coalesced:
// each stage instr covers 8 full 128B rows (16 fully-consumed 64B lines).
__global__ __launch_bounds__(512, 2) void gemm1_kernel(
    const u16* __restrict__ Xg, const u16* __restrict__ W1T,
    const float* __restrict__ B1,
    const int* __restrict__ counts, const int* __restrict__ offsets,
    const int* __restrict__ map_e, const int* __restrict__ map_r,
    const int* __restrict__ nT, u16* __restrict__ H)
{
  __shared__ __align__(16) char lds[2 * 65536]; // [buf][A 32KB | B 32KB]
  const int gid   = xcd_swz(blockIdx.x, gridDim.x);
  const int n_idx = gid / MT256;
  const int t_idx = gid - n_idx * MT256;
  if (t_idx >= nT[0]) return;
  const int e    = map_e[t_idx];
  const int row0 = map_r[t_idx];
  const int cnt  = counts[e];
  const int off  = offsets[e];
  const int n0   = n_idx * 256;

  const int tid = threadIdx.x, wave = tid >> 6, lane = tid & 63;
  const int lr = lane & 15, lq = lane >> 4;
  const int wr = wave >> 2, wc = wave & 3;   // 2M x 4N
  const int l3 = lane >> 3;                  // 0..7
  const int usrc = (lane & 7) ^ l3;          // swizzled source unit

  // per-instr staging sources (rows wave*32 + i*8 + l3)
  const char* gA[4]; const char* gB[4];
  #pragma unroll
  for (int i = 0; i < 4; i++) {
    int rA = imin(off + row0 + wave * 32 + i * 8 + l3, NSLOT - 1);
    gA[i] = (const char*)Xg + (size_t)rA * 2048 + usrc * 16;
    int rB = e * FDIM + n0 + wave * 32 + i * 8 + l3;
    gB[i] = (const char*)W1T + (size_t)rB * 2048 + usrc * 16;
  }
  const int dbase = wave * 4096 + lane * 16; // (wave*32 rows)*128B + lane*16

  auto stage = [&](int buf, int kByte) {
    #pragma unroll
    for (int i = 0; i < 4; i++)
      gload16(gA[i] + kByte, lds + buf * 65536 + dbase + i * 1024);
    #pragma unroll
    for (int i = 0; i < 4; i++)
      gload16(gB[i] + kByte, lds + buf * 65536 + 32768 + dbase + i * 1024);
  };

  f32x4 acc[8][4] = {};
  auto compute = [&](int buf) {
    const u16* A  = (const u16*)(lds + buf * 65536);
    const u16* Bp = (const u16*)(lds + buf * 65536 + 32768);
    #pragma unroll
    for (int ks = 0; ks < 2; ks++) {
      const int uu = (((ks * 4 + lq) ^ (lr & 7))) * 8; // swizzled unit, elems
      short8 a[8], b[4];
      #pragma unroll
      for (int n = 0; n < 4; n++)
        b[n] = *(const short8*)&Bp[(wc * 64 + n * 16 + lr) * 64 + uu];
      #pragma unroll
      for (int m = 0; m < 8; m++)
        a[m] = *(const short8*)&A[(wr * 128 + m * 16 + lr) * 64 + uu];
      #pragma unroll
      for (int m = 0; m < 8; m++)
        #pragma unroll
        for (int n = 0; n < 4; n++)
          acc[m][n] = __builtin_amdgcn_mfma_f32_16x16x32_bf16(a[m], b[n], acc[m][n], 0, 0, 0);
    }
  };

  // NT = 16 K-steps (K=1024, BK=64); kByte step = 128
  stage(0, 0);
  VM0; SCHED0; SBAR; SCHED0;
  #pragma unroll 1
  for (int t = 0; t < 16; t++) {
    if (t < 15) stage((t + 1) & 1, (t + 1) * 128);
    compute(t & 1);
    SCHED0; VM0; SCHED0; SBAR; SCHED0;
  }

  // epilogue: gelu + store bf16
  #pragma unroll
  for (int m = 0; m < 8; m++) {
    int rloc = wr * 128 + m * 16 + lq * 4;
    #pragma unroll
    for (int j = 0; j < 4; j++) {
      int r = rloc + j;
      if (row0 + r < cnt) {
        u16* Hrow = H + (size_t)(off + row0 + r) * FDIM;
        #pragma unroll
        for (int n = 0; n < 4; n++) {
          int col = n0 + wc * 64 + n * 16 + lr;
          float v = acc[m][n][j] + B1[e * FDIM + col];
          Hrow[col] = f2bf(gelu_fast(v));
        }
      }
    }
  }
}

// ---------------- grouped GEMM2 + fused combine ----------------
// 256x256, BK=64, split-K=2 (32 steps each), dbuf 128KB, same 2-phase loop.
// out[tok] += wgt * (H@W2 + b2) via f32 atomics (exactly 2 adds/element).
__global__ __launch_bounds__(512, 2) void gemm2_kernel(
    const u16* __restrict__ H, const u16* __restrict__ W2T,
    const float* __restrict__ B2,
    const int* __restrict__ counts, const int* __restrict__ offsets,
    const int* __restrict__ slot_token, const float* __restrict__ slot_weight,
    const int* __restrict__ map_e, const int* __restrict__ map_r,
    const int* __restrict__ nT, float* __restrict__ out)
{
  __shared__ __align__(16) char lds[2 * 65536];
  const int gid   = xcd_swz(blockIdx.x, gridDim.x);
  const int sp    = gid / (4 * MT256);
  const int rem   = gid - sp * 4 * MT256;
  const int n_idx = rem / MT256;
  const int t_idx = rem - n_idx * MT256;
  if (t_idx >= nT[0]) return;
  const int e    = map_e[t_idx];
  const int row0 = map_r[t_idx];
  const int cnt  = counts[e];
  const int off  = offsets[e];
  const int n0   = n_idx * 256;
  const int kbase = sp * 4096;  // bytes: split sp covers k elems [sp*2048, +2048)

  const int tid = threadIdx.x, wave = tid >> 6, lane = tid & 63;
  const int lr = lane & 15, lq = lane >> 4;
  const int wr = wave >> 2, wc = wave & 3;   // 2M x 4N
  const int l3 = lane >> 3;
  const int usrc = (lane & 7) ^ l3;

  const char* gA[4]; const char* gB[4];
  #pragma unroll
  for (int i = 0; i < 4; i++) {
    int rA = imin(off + row0 + wave * 32 + i * 8 + l3, NSLOT - 1);
    gA[i] = (const char*)H + (size_t)rA * 8192 + kbase + usrc * 16;
    int rB = e * DDIM + n0 + wave * 32 + i * 8 + l3;
    gB[i] = (const char*)W2T + (size_t)rB * 8192 + kbase + usrc * 16;
  }
  const int dbase = wave * 4096 + lane * 16;

  auto stage = [&](int buf, int kByte) {
    #pragma unroll
    for (int i = 0; i < 4; i++)
      gload16(gA[i] + kByte, lds + buf * 65536 + dbase + i * 1024);
    #pragma unroll
    for (int i = 0; i < 4; i++)
      gload16(gB[i] + kByte, lds + buf * 65536 + 32768 + dbase + i * 1024);
  };

  f32x4 acc[8][4] = {};
  auto compute = [&](int buf) {
    const u16* A  = (const u16*)(lds + buf * 65536);
    const u16* Bp = (const u16*)(lds + buf * 65536 + 32768);
    #pragma unroll
    for (int ks = 0; ks < 2; ks++) {
      const int uu = (((ks * 4 + lq) ^ (lr & 7))) * 8;
      short8 a[8], b[4];
      #pragma unroll
      for (int n = 0; n < 4; n++)
        b[n] = *(const short8*)&Bp[(wc * 64 + n * 16 + lr) * 64 + uu];
      #pragma unroll
      for (int m = 0; m < 8; m++)
        a[m] = *(const short8*)&A[(wr * 128 + m * 16 + lr) * 64 + uu];
      #pragma unroll
      for (int m = 0; m < 8; m++)
        #pragma unroll
        for (int n = 0; n < 4; n++)
          acc[m][n] = __builtin_amdgcn_mfma_f32_16x16x32_bf16(a[m], b[n], acc[m][n], 0, 0, 0);
    }
  };

  // NT = 32 K-steps per split (K=2048, BK=64)
  stage(0, 0);
  VM0; SCHED0; SBAR; SCHED0;
  #pragma unroll 1
  for (int t = 0; t < 32; t++) {
    if (t < 31) stage((t + 1) & 1, (t + 1) * 128);
    compute(t & 1);
    SCHED0; VM0; SCHED0; SBAR; SCHED0;
  }

  #pragma unroll
  for (int m = 0; m < 8; m++) {
    int rloc = wr * 128 + m * 16 + lq * 4;
    #pragma unroll
    for (int j = 0; j < 4; j++) {
      int r = rloc + j;
      if (row0 + r >= cnt) continue;
      int s = off + row0 + r;
      int tok = slot_token[s];
      float wgt = slot_weight[s];
      #pragma unroll
      for (int n = 0; n < 4; n++) {
        int col = n0 + wc * 64 + n * 16 + lr;
        float v = acc[m][n][j];
        if (sp == 0) v += B2[e * DDIM + col];
        atomicAdd(&out[(size_t)tok * DDIM + col], wgt * v);
      }
    }
  }
}

extern "C" void kernel_launch(void* const* d_in, const int* in_sizes, int n_in,
                              void* d_out, int out_size, void* d_ws, size_t ws_size,
                              hipStream_t stream)
{
  (void)in_sizes; (void)n_in; (void)ws_size;
  const float* x  = (const float*)d_in[0];
  const float* gw = (const float*)d_in[1];
  const float* gb = (const float*)d_in[2];
  const float* w1 = (const float*)d_in[3];
  const float* b1 = (const float*)d_in[4];
  const float* w2 = (const float*)d_in[5];
  const float* b2 = (const float*)d_in[6];

  char* ws = (char*)d_ws;
  int*   counts = (int*)(ws + 0);
  int*   offp   = (int*)(ws + 64);
  int*   nT     = (int*)(ws + 128);
  int*   map_e  = (int*)(ws + 256);
  int*   map_r  = (int*)(ws + 1024);

  size_t p = 2048;
  int*   sel   = (int*)(ws + p);   p += (size_t)T_TOK * 2 * 4;
  float* wts   = (float*)(ws + p); p += (size_t)T_TOK * 2 * 4;
  int*   stok  = (int*)(ws + p);   p += (size_t)NSLOT * 4;
  float* swgt  = (float*)(ws + p); p += (size_t)NSLOT * 4;
  p = (p + 1048575) & ~(size_t)1048575;
  u16*   xb    = (u16*)(ws + p);   p += (size_t)T_TOK * DDIM * 2;
  u16*   Xg    = (u16*)(ws + p);   p += (size_t)NSLOT * DDIM * 2;
  u16*   w1t   = (u16*)(ws + p);   p += (size_t)NEXP * DDIM * FDIM * 2;
  u16*   w2t   = (u16*)(ws + p);   p += (size_t)NEXP * DDIM * FDIM * 2;
  u16*   Hbuf  = (u16*)(ws + p);   // NSLOT rows x FDIM bf16 (128 MB)

  hipMemsetAsync(ws, 0, 256, stream);
  hipMemsetAsync(d_out, 0, (size_t)out_size * sizeof(float), stream);
  router_kernel<<<T_TOK / 4, 256, 0, stream>>>(x, gw, gb, xb, counts, sel, wts);
  scan_assign_kernel<<<1, 256, 0, stream>>>(counts, sel, wts, offp, map_e, map_r, nT, stok, swgt);
  xgather_kernel<<<NSLOT / 2, 256, 0, stream>>>(xb, stok, Xg);
  // W2 first so w1t is cache-warm when gemm1 starts
  wtrans_kernel<<<dim3(DDIM / 64, FDIM / 128, NEXP), 256, 0, stream>>>(w2, w2t, FDIM, DDIM);
  wtrans_kernel<<<dim3(FDIM / 64, DDIM / 128, NEXP), 256, 0, stream>>>(w1, w1t, DDIM, FDIM);

  gemm1_kernel<<<(FDIM / 256) * MT256, 512, 0, stream>>>(
      Xg, w1t, b1, counts, offp, map_e, map_r, nT, Hbuf);
  gemm2_kernel<<<2 * (DDIM / 256) * MT256, 512, 0, stream>>>(
      Hbuf, w2t, b2, counts, offp, stok, swgt, map_e, map_r, nT, (float*)d_out);
}

// Round 9
// 845.982 us; speedup vs baseline: 1.2670x; 1.0148x over previous
//
#include <hip/hip_runtime.h>
#include <math.h>

#define T_TOK 8192
#define DDIM  1024
#define FDIM  4096
#define NEXP  8
#define MAXT  136   // max 128-row tiles over all experts
#define NSLOT (2 * T_TOK)

typedef __attribute__((ext_vector_type(8))) short short8;
typedef __attribute__((ext_vector_type(4))) float f32x4;
typedef unsigned short u16;
typedef unsigned int   u32;

typedef const __attribute__((address_space(1))) u32* gp_t;
typedef       __attribute__((address_space(3))) u32* lp_t;

__device__ __forceinline__ void gload16(const void* g, void* l) {
  __builtin_amdgcn_global_load_lds((gp_t)g, (lp_t)l, 16, 0, 0);
}

#define VM6 asm volatile("s_waitcnt vmcnt(6)" ::: "memory")
#define VM0 asm volatile("s_waitcnt vmcnt(0)" ::: "memory")
#define SBAR __builtin_amdgcn_s_barrier()
#define SCHED0 __builtin_amdgcn_sched_barrier(0)

__device__ __forceinline__ u16 f2bf(float f) {
  u32 u = __float_as_uint(f);
  u = u + 0x7FFFu + ((u >> 16) & 1u);
  return (u16)(u >> 16);
}

__device__ __forceinline__ int imin(int a, int b) { return a < b ? a : b; }

// fast gelu (tanh form); |err| vs exact-erf gelu ~1e-3 << 0.0398 threshold
__device__ __forceinline__ float gelu_fast(float v) {
  float u = 0.7978845608f * (v + 0.044715f * v * v * v);
  float t2 = __expf(2.f * u);
  float th = 1.f - 2.f / (t2 + 1.f);
  return 0.5f * v * (1.f + th);
}

// bijective XCD chunking (m204)
__device__ __forceinline__ int xcd_swz(int orig, int nwg) {
  int xcd = orig & 7;
  int q = nwg >> 3, r = nwg & 7;
  int base = (xcd < r) ? xcd * (q + 1) : r * (q + 1) + (xcd - r) * q;
  return base + (orig >> 3);
}

// ---------------- router (+ x->bf16 fused): one wave per token ----------------
__global__ __launch_bounds__(256) void router_kernel(
    const float* __restrict__ x, const float* __restrict__ gw,
    const float* __restrict__ gb, u16* __restrict__ xb,
    int* __restrict__ counts, int* __restrict__ sel, float* __restrict__ wts)
{
  const int t    = blockIdx.x * 4 + (threadIdx.x >> 6);
  const int lane = threadIdx.x & 63;
  const float* xr = x + (size_t)t * DDIM;
  u16* xbr = xb + (size_t)t * DDIM;
  float lg[NEXP];
  #pragma unroll
  for (int e = 0; e < NEXP; e++) lg[e] = 0.f;
  #pragma unroll
  for (int i = 0; i < 4; i++) {
    int d0 = i * 256 + lane * 4;
    float4 v = *(const float4*)(xr + d0);
    ushort4 o;
    o.x = f2bf(v.x); o.y = f2bf(v.y); o.z = f2bf(v.z); o.w = f2bf(v.w);
    *(ushort4*)(xbr + d0) = o;
    const float* g = gw + (size_t)d0 * NEXP;
    #pragma unroll
    for (int e = 0; e < NEXP; e++)
      lg[e] += v.x * g[e] + v.y * g[NEXP + e] + v.z * g[2 * NEXP + e] + v.w * g[3 * NEXP + e];
  }
  #pragma unroll
  for (int off = 32; off > 0; off >>= 1) {
    #pragma unroll
    for (int e = 0; e < NEXP; e++) lg[e] += __shfl_down(lg[e], off);
  }
  if (lane == 0) {
    float v0 = -1e30f, v1 = -1e30f; int s0 = 0, s1 = 0;
    #pragma unroll
    for (int e = 0; e < NEXP; e++) {
      float v = lg[e] + gb[e];
      if (v > v0) { v1 = v0; s1 = s0; v0 = v; s0 = e; }
      else if (v > v1) { v1 = v; s1 = e; }
    }
    float a  = expf(v1 - v0);
    float w0 = 1.f / (1.f + a);
    sel[t * 2] = s0; sel[t * 2 + 1] = s1;
    wts[t * 2] = w0; wts[t * 2 + 1] = 1.f - w0;
    atomicAdd(&counts[s0], 1); atomicAdd(&counts[s1], 1);
  }
}

// ---------------- scan + tile map (128-row tiles) + slot assignment ----------
__global__ __launch_bounds__(256) void scan_assign_kernel(
    const int* __restrict__ counts, const int* __restrict__ sel,
    const float* __restrict__ wts,
    int* __restrict__ offsets, int* __restrict__ map_e, int* __restrict__ map_r,
    int* __restrict__ nT, int* __restrict__ stok, float* __restrict__ swgt)
{
  __shared__ int spos[NEXP];
  if (threadIdx.x == 0) {
    int run = 0, nt = 0;
    for (int e = 0; e < NEXP; e++) {
      offsets[e] = run; spos[e] = run;
      int c = counts[e];
      int ntile = (c + 127) >> 7;
      for (int i = 0; i < ntile; i++) { map_e[nt] = e; map_r[nt] = i * 128; nt++; }
      run += c;
    }
    nT[0] = nt;
  }
  __syncthreads();
  for (int t = threadIdx.x; t < T_TOK; t += 256) {
    #pragma unroll
    for (int k = 0; k < 2; k++) {
      int e = sel[t * 2 + k];
      int p = atomicAdd(&spos[e], 1);
      stok[p] = t; swgt[p] = wts[t * 2 + k];
    }
  }
}

// ---------------- gather X rows into slot order: Xg[s] = xb[stok[s]] --------
__global__ __launch_bounds__(256) void xgather_kernel(
    const u16* __restrict__ xb, const int* __restrict__ stok,
    u16* __restrict__ Xg)
{
  const int s = blockIdx.x * 2 + (threadIdx.x >> 7);
  const int u = threadIdx.x & 127;
  int tok = stok[s]; if ((u32)tok >= T_TOK) tok = 0;
  const uint4* src = (const uint4*)(xb + (size_t)tok * DDIM);
  uint4* dst = (uint4*)(Xg + (size_t)s * DDIM);
  dst[u] = src[u];
}

// ---- weight transpose + bf16: in [M][N] f32 -> out [N][M] bf16 ----
__global__ __launch_bounds__(256) void wtrans_kernel(
    const float* __restrict__ in, u16* __restrict__ out, int M, int N)
{
  const int e = blockIdx.z;
  in  += (size_t)e * M * N;
  out += (size_t)e * M * N;
  const int r0 = blockIdx.y * 128;  // M dim
  const int c0 = blockIdx.x * 64;   // N dim
  __shared__ float tile[128][65];
  const int tid = threadIdx.x;
  const int lr = tid >> 4;
  const int lc = (tid & 15) * 4;
  #pragma unroll
  for (int p = 0; p < 8; p++) {
    int r = p * 16 + lr;
    float4 v = *(const float4*)(in + (size_t)(r0 + r) * N + (c0 + lc));
    tile[r][lc] = v.x; tile[r][lc + 1] = v.y; tile[r][lc + 2] = v.z; tile[r][lc + 3] = v.w;
  }
  __syncthreads();
  const int oc = tid >> 4;
  const int om = (tid & 15) * 8;
  #pragma unroll
  for (int p = 0; p < 4; p++) {
    int c = p * 16 + oc;
    short8 o;
    #pragma unroll
    for (int j = 0; j < 8; j++) o[j] = (short)f2bf(tile[om + j][c]);
    *(short8*)(out + (size_t)(c0 + c) * M + (r0 + om)) = o;
  }
}

// ---------------- grouped GEMM1: H = gelu(Xg@W1 + b1) ----------------
// M=128 N=256 BK=64, 8 waves (2Mx4N), ring-3 LDS (144KB), counted vmcnt(6)
// steady-state (never 0 in main loop). LDS rows 128B, XOR-unit swizzle
// (unit ^= row&7): src-swizzled global addr + linear gload_lds dest +
// swizzled ds_read (rule #21). 2-way bank alias only (free).
__global__ __launch_bounds__(512, 2) void gemm1_kernel(
    const u16* __restrict__ Xg, const u16* __restrict__ W1T,
    const float* __restrict__ B1,
    const int* __restrict__ counts, const int* __restrict__ offsets,
    const int* __restrict__ map_e, const int* __restrict__ map_r,
    const int* __restrict__ nT, u16* __restrict__ H)
{
  __shared__ __align__(16) char lds[3 * 49152]; // slot: [A 16KB | B 32KB]
  const int gid   = xcd_swz(blockIdx.x, gridDim.x);
  const int n_idx = gid / MAXT;          // 0..15
  const int t_idx = gid - n_idx * MAXT;
  if (t_idx >= nT[0]) return;
  const int e    = map_e[t_idx];
  const int row0 = map_r[t_idx];
  const int cnt  = counts[e];
  const int off  = offsets[e];
  const int n0   = n_idx * 256;

  const int tid = threadIdx.x, wave = tid >> 6, lane = tid & 63;
  const int lr = lane & 15, lq = lane >> 4;
  const int wr = wave >> 2, wc = wave & 3;   // 2M x 4N
  const int l3 = lane >> 3;                  // 0..7
  const int usrc = (lane & 7) ^ l3;          // swizzled source unit

  // staging sources: A rows w*16 + i*8 + l3 (i<2); B rows w*32 + i*8 + l3 (i<4)
  const char* gA[2]; const char* gB[4];
  #pragma unroll
  for (int i = 0; i < 2; i++) {
    int rA = imin(off + row0 + wave * 16 + i * 8 + l3, NSLOT - 1);
    gA[i] = (const char*)Xg + (size_t)rA * 2048 + usrc * 16;
  }
  #pragma unroll
  for (int i = 0; i < 4; i++) {
    int rB = e * FDIM + n0 + wave * 32 + i * 8 + l3;
    gB[i] = (const char*)W1T + (size_t)rB * 2048 + usrc * 16;
  }

  auto stage = [&](int slot, int kByte) {
    char* base = lds + slot * 49152;
    #pragma unroll
    for (int i = 0; i < 2; i++)
      gload16(gA[i] + kByte, base + wave * 2048 + i * 1024 + lane * 16);
    #pragma unroll
    for (int i = 0; i < 4; i++)
      gload16(gB[i] + kByte, base + 16384 + wave * 4096 + i * 1024 + lane * 16);
  };

  f32x4 acc[4][4] = {};
  auto compute = [&](int slot) {
    const u16* A  = (const u16*)(lds + slot * 49152);
    const u16* Bp = (const u16*)(lds + slot * 49152 + 16384);
    #pragma unroll
    for (int ks = 0; ks < 2; ks++) {
      const int uu = ((ks * 4 + lq) ^ (lr & 7)) * 8; // swizzled unit, elems
      short8 a[4], b[4];
      #pragma unroll
      for (int n = 0; n < 4; n++)
        b[n] = *(const short8*)&Bp[(wc * 64 + n * 16 + lr) * 64 + uu];
      #pragma unroll
      for (int m = 0; m < 4; m++)
        a[m] = *(const short8*)&A[(wr * 64 + m * 16 + lr) * 64 + uu];
      #pragma unroll
      for (int m = 0; m < 4; m++)
        #pragma unroll
        for (int n = 0; n < 4; n++)
          acc[m][n] = __builtin_amdgcn_mfma_f32_16x16x32_bf16(a[m], b[n], acc[m][n], 0, 0, 0);
    }
  };

  // NT = 16 K-steps (K=1024, BK=64); kByte step 128. Ring-3, lead-2.
  stage(0, 0); stage(1, 128);
  VM6; SCHED0; SBAR; SCHED0;
  #pragma unroll 1
  for (int t = 0; t < 16; t++) {
    if (t + 2 < 16) stage((t + 2) % 3, (t + 2) * 128);
    compute(t % 3);
    SCHED0;
    if (t + 2 < 16)       { VM6; }
    else if (t + 2 == 16) { VM0; }
    SCHED0; SBAR; SCHED0;
  }

  // epilogue: gelu + store bf16
  #pragma unroll
  for (int m = 0; m < 4; m++) {
    int rloc = wr * 64 + m * 16 + lq * 4;
    #pragma unroll
    for (int j = 0; j < 4; j++) {
      int r = rloc + j;
      if (row0 + r < cnt) {
        u16* Hrow = H + (size_t)(off + row0 + r) * FDIM;
        #pragma unroll
        for (int n = 0; n < 4; n++) {
          int col = n0 + wc * 64 + n * 16 + lr;
          float v = acc[m][n][j] + B1[e * FDIM + col];
          Hrow[col] = f2bf(gelu_fast(v));
        }
      }
    }
  }
}

// ---------------- grouped GEMM2 + fused combine ----------------
// M=128 N=256 BK=64, split-K=2 (32 steps each), ring-3, counted vmcnt(6).
// out[tok] += wgt * (H@W2 + b2) via f32 atomics (exactly 2 adds/element).
__global__ __launch_bounds__(512, 2) void gemm2_kernel(
    const u16* __restrict__ H, const u16* __restrict__ W2T,
    const float* __restrict__ B2,
    const int* __restrict__ counts, const int* __restrict__ offsets,
    const int* __restrict__ slot_token, const float* __restrict__ slot_weight,
    const int* __restrict__ map_e, const int* __restrict__ map_r,
    const int* __restrict__ nT, float* __restrict__ out)
{
  __shared__ __align__(16) char lds[3 * 49152];
  const int gid   = xcd_swz(blockIdx.x, gridDim.x);
  const int sp    = gid / (4 * MAXT);
  const int rem   = gid - sp * 4 * MAXT;
  const int n_idx = rem / MAXT;          // 0..3
  const int t_idx = rem - n_idx * MAXT;
  if (t_idx >= nT[0]) return;
  const int e    = map_e[t_idx];
  const int row0 = map_r[t_idx];
  const int cnt  = counts[e];
  const int off  = offsets[e];
  const int n0   = n_idx * 256;
  const int kbase = sp * 4096;  // bytes: split sp covers k elems [sp*2048, +2048)

  const int tid = threadIdx.x, wave = tid >> 6, lane = tid & 63;
  const int lr = lane & 15, lq = lane >> 4;
  const int wr = wave >> 2, wc = wave & 3;   // 2M x 4N
  const int l3 = lane >> 3;
  const int usrc = (lane & 7) ^ l3;

  const char* gA[2]; const char* gB[4];
  #pragma unroll
  for (int i = 0; i < 2; i++) {
    int rA = imin(off + row0 + wave * 16 + i * 8 + l3, NSLOT - 1);
    gA[i] = (const char*)H + (size_t)rA * 8192 + kbase + usrc * 16;
  }
  #pragma unroll
  for (int i = 0; i < 4; i++) {
    int rB = e * DDIM + n0 + wave * 32 + i * 8 + l3;
    gB[i] = (const char*)W2T + (size_t)rB * 8192 + kbase + usrc * 16;
  }

  auto stage = [&](int slot, int kByte) {
    char* base = lds + slot * 49152;
    #pragma unroll
    for (int i = 0; i < 2; i++)
      gload16(gA[i] + kByte, base + wave * 2048 + i * 1024 + lane * 16);
    #pragma unroll
    for (int i = 0; i < 4; i++)
      gload16(gB[i] + kByte, base + 16384 + wave * 4096 + i * 1024 + lane * 16);
  };

  f32x4 acc[4][4] = {};
  auto compute = [&](int slot) {
    const u16* A  = (const u16*)(lds + slot * 49152);
    const u16* Bp = (const u16*)(lds + slot * 49152 + 16384);
    #pragma unroll
    for (int ks = 0; ks < 2; ks++) {
      const int uu = ((ks * 4 + lq) ^ (lr & 7)) * 8;
      short8 a[4], b[4];
      #pragma unroll
      for (int n = 0; n < 4; n++)
        b[n] = *(const short8*)&Bp[(wc * 64 + n * 16 + lr) * 64 + uu];
      #pragma unroll
      for (int m = 0; m < 4; m++)
        a[m] = *(const short8*)&A[(wr * 64 + m * 16 + lr) * 64 + uu];
      #pragma unroll
      for (int m = 0; m < 4; m++)
        #pragma unroll
        for (int n = 0; n < 4; n++)
          acc[m][n] = __builtin_amdgcn_mfma_f32_16x16x32_bf16(a[m], b[n], acc[m][n], 0, 0, 0);
    }
  };

  // NT = 32 K-steps per split (K=2048, BK=64). Ring-3, lead-2.
  stage(0, 0); stage(1, 128);
  VM6; SCHED0; SBAR; SCHED0;
  #pragma unroll 1
  for (int t = 0; t < 32; t++) {
    if (t + 2 < 32) stage((t + 2) % 3, (t + 2) * 128);
    compute(t % 3);
    SCHED0;
    if (t + 2 < 32)       { VM6; }
    else if (t + 2 == 32) { VM0; }
    SCHED0; SBAR; SCHED0;
  }

  #pragma unroll
  for (int m = 0; m < 4; m++) {
    int rloc = wr * 64 + m * 16 + lq * 4;
    #pragma unroll
    for (int j = 0; j < 4; j++) {
      int r = rloc + j;
      if (row0 + r >= cnt) continue;
      int s = off + row0 + r;
      int tok = slot_token[s];
      float wgt = slot_weight[s];
      #pragma unroll
      for (int n = 0; n < 4; n++) {
        int col = n0 + wc * 64 + n * 16 + lr;
        float v = acc[m][n][j];
        if (sp == 0) v += B2[e * DDIM + col];
        atomicAdd(&out[(size_t)tok * DDIM + col], wgt * v);
      }
    }
  }
}

extern "C" void kernel_launch(void* const* d_in, const int* in_sizes, int n_in,
                              void* d_out, int out_size, void* d_ws, size_t ws_size,
                              hipStream_t stream)
{
  (void)in_sizes; (void)n_in; (void)ws_size;
  const float* x  = (const float*)d_in[0];
  const float* gw = (const float*)d_in[1];
  const float* gb = (const float*)d_in[2];
  const float* w1 = (const float*)d_in[3];
  const float* b1 = (const float*)d_in[4];
  const float* w2 = (const float*)d_in[5];
  const float* b2 = (const float*)d_in[6];

  char* ws = (char*)d_ws;
  int*   counts = (int*)(ws + 0);
  int*   offp   = (int*)(ws + 64);
  int*   nT     = (int*)(ws + 128);
  int*   map_e  = (int*)(ws + 256);
  int*   map_r  = (int*)(ws + 1024);

  size_t p = 2048;
  int*   sel   = (int*)(ws + p);   p += (size_t)T_TOK * 2 * 4;
  float* wts   = (float*)(ws + p); p += (size_t)T_TOK * 2 * 4;
  int*   stok  = (int*)(ws + p);   p += (size_t)NSLOT * 4;
  float* swgt  = (float*)(ws + p); p += (size_t)NSLOT * 4;
  p = (p + 1048575) & ~(size_t)1048575;
  u16*   xb    = (u16*)(ws + p);   p += (size_t)T_TOK * DDIM * 2;
  u16*   Xg    = (u16*)(ws + p);   p += (size_t)NSLOT * DDIM * 2;
  u16*   w1t   = (u16*)(ws + p);   p += (size_t)NEXP * DDIM * FDIM * 2;
  u16*   w2t   = (u16*)(ws + p);   p += (size_t)NEXP * DDIM * FDIM * 2;
  u16*   Hbuf  = (u16*)(ws + p);   // NSLOT rows x FDIM bf16 (128 MB)

  hipMemsetAsync(ws, 0, 256, stream);
  hipMemsetAsync(d_out, 0, (size_t)out_size * sizeof(float), stream);
  router_kernel<<<T_TOK / 4, 256, 0, stream>>>(x, gw, gb, xb, counts, sel, wts);
  scan_assign_kernel<<<1, 256, 0, stream>>>(counts, sel, wts, offp, map_e, map_r, nT, stok, swgt);
  xgather_kernel<<<NSLOT / 2, 256, 0, stream>>>(xb, stok, Xg);
  // W2 first so w1t is cache-warm when gemm1 starts
  wtrans_kernel<<<dim3(DDIM / 64, FDIM / 128, NEXP), 256, 0, stream>>>(w2, w2t, FDIM, DDIM);
  wtrans_kernel<<<dim3(FDIM / 64, DDIM / 128, NEXP), 256, 0, stream>>>(w1, w1t, DDIM, FDIM);

  gemm1_kernel<<<(FDIM / 256) * MAXT, 512, 0, stream>>>(
      Xg, w1t, b1, counts, offp, map_e, map_r, nT, Hbuf);
  gemm2_kernel<<<2 * (DDIM / 256) * MAXT, 512, 0, stream>>>(
      Hbuf, w2t, b2, counts, offp, stok, swgt, map_e, map_r, nT, (float*)d_out);
}

// Round 10
// 842.236 us; speedup vs baseline: 1.2727x; 1.0044x over previous
//
#include <hip/hip_runtime.h>
#include <math.h>

#define T_TOK 8192
#define DDIM  1024
#define FDIM  4096
#define NEXP  8
#define MT256 72
#define NSLOT (2 * T_TOK)

typedef __attribute__((ext_vector_type(8))) short short8;
typedef __attribute__((ext_vector_type(4))) float f32x4;
typedef unsigned short u16;
typedef unsigned int   u32;

typedef const __attribute__((address_space(1))) u32* gp_t;
typedef       __attribute__((address_space(3))) u32* lp_t;

__device__ __forceinline__ void gload16(const void* g, void* l) {
  __builtin_amdgcn_global_load_lds((gp_t)g, (lp_t)l, 16, 0, 0);
}

#define VM8 asm volatile("s_waitcnt vmcnt(8)" ::: "memory")
#define VM6 asm volatile("s_waitcnt vmcnt(6)" ::: "memory")
#define VM4 asm volatile("s_waitcnt vmcnt(4)" ::: "memory")
#define VM2 asm volatile("s_waitcnt vmcnt(2)" ::: "memory")
#define VM0 asm volatile("s_waitcnt vmcnt(0)" ::: "memory")
#define SBAR __builtin_amdgcn_s_barrier()
#define SCHED0 __builtin_amdgcn_sched_barrier(0)

__device__ __forceinline__ u16 f2bf(float f) {
  u32 u = __float_as_uint(f);
  u = u + 0x7FFFu + ((u >> 16) & 1u);
  return (u16)(u >> 16);
}

__device__ __forceinline__ int imin(int a, int b) { return a < b ? a : b; }

__device__ __forceinline__ float gelu_fast(float v) {
  float u = 0.7978845608f * (v + 0.044715f * v * v * v);
  float t2 = __expf(2.f * u);
  float th = 1.f - 2.f / (t2 + 1.f);
  return 0.5f * v * (1.f + th);
}

// bijective XCD chunking (m204)
__device__ __forceinline__ int xcd_swz(int orig, int nwg) {
  int xcd = orig & 7;
  int q = nwg >> 3, r = nwg & 7;
  int base = (xcd < r) ? xcd * (q + 1) : r * (q + 1) + (xcd - r) * q;
  return base + (orig >> 3);
}

// ---------------- router (+ x->bf16 fused): one wave per token ----------------
__global__ __launch_bounds__(256) void router_kernel(
    const float* __restrict__ x, const float* __restrict__ gw,
    const float* __restrict__ gb, u16* __restrict__ xb,
    int* __restrict__ counts, int* __restrict__ sel, float* __restrict__ wts)
{
  const int t    = blockIdx.x * 4 + (threadIdx.x >> 6);
  const int lane = threadIdx.x & 63;
  const float* xr = x + (size_t)t * DDIM;
  u16* xbr = xb + (size_t)t * DDIM;
  float lg[NEXP];
  #pragma unroll
  for (int e = 0; e < NEXP; e++) lg[e] = 0.f;
  #pragma unroll
  for (int i = 0; i < 4; i++) {
    int d0 = i * 256 + lane * 4;
    float4 v = *(const float4*)(xr + d0);
    ushort4 o;
    o.x = f2bf(v.x); o.y = f2bf(v.y); o.z = f2bf(v.z); o.w = f2bf(v.w);
    *(ushort4*)(xbr + d0) = o;
    const float* g = gw + (size_t)d0 * NEXP;
    #pragma unroll
    for (int e = 0; e < NEXP; e++)
      lg[e] += v.x * g[e] + v.y * g[NEXP + e] + v.z * g[2 * NEXP + e] + v.w * g[3 * NEXP + e];
  }
  #pragma unroll
  for (int off = 32; off > 0; off >>= 1) {
    #pragma unroll
    for (int e = 0; e < NEXP; e++) lg[e] += __shfl_down(lg[e], off);
  }
  if (lane == 0) {
    float v0 = -1e30f, v1 = -1e30f; int s0 = 0, s1 = 0;
    #pragma unroll
    for (int e = 0; e < NEXP; e++) {
      float v = lg[e] + gb[e];
      if (v > v0) { v1 = v0; s1 = s0; v0 = v; s0 = e; }
      else if (v > v1) { v1 = v; s1 = e; }
    }
    float a  = expf(v1 - v0);
    float w0 = 1.f / (1.f + a);
    sel[t * 2] = s0; sel[t * 2 + 1] = s1;
    wts[t * 2] = w0; wts[t * 2 + 1] = 1.f - w0;
    atomicAdd(&counts[s0], 1); atomicAdd(&counts[s1], 1);
  }
}

// ---------------- scan + tile map (256-row tiles) + slot assignment ----------
__global__ __launch_bounds__(256) void scan_assign_kernel(
    const int* __restrict__ counts, const int* __restrict__ sel,
    const float* __restrict__ wts,
    int* __restrict__ offsets, int* __restrict__ map_e, int* __restrict__ map_r,
    int* __restrict__ nT, int* __restrict__ stok, float* __restrict__ swgt)
{
  __shared__ int spos[NEXP];
  if (threadIdx.x == 0) {
    int run = 0, nt = 0;
    for (int e = 0; e < NEXP; e++) {
      offsets[e] = run; spos[e] = run;
      int c = counts[e];
      int ntile = (c + 255) >> 8;
      for (int i = 0; i < ntile; i++) { map_e[nt] = e; map_r[nt] = i * 256; nt++; }
      run += c;
    }
    nT[0] = nt;
  }
  __syncthreads();
  for (int t = threadIdx.x; t < T_TOK; t += 256) {
    #pragma unroll
    for (int k = 0; k < 2; k++) {
      int e = sel[t * 2 + k];
      int p = atomicAdd(&spos[e], 1);
      stok[p] = t; swgt[p] = wts[t * 2 + k];
    }
  }
}

// ---------------- gather X rows into slot order: Xg[s] = xb[stok[s]] --------
__global__ __launch_bounds__(256) void xgather_kernel(
    const u16* __restrict__ xb, const int* __restrict__ stok,
    u16* __restrict__ Xg)
{
  const int s = blockIdx.x * 2 + (threadIdx.x >> 7);
  const int u = threadIdx.x & 127;
  int tok = stok[s]; if ((u32)tok >= T_TOK) tok = 0;
  const uint4* src = (const uint4*)(xb + (size_t)tok * DDIM);
  uint4* dst = (uint4*)(Xg + (size_t)s * DDIM);
  dst[u] = src[u];
}

// ---- weight transpose + bf16: in [M][N] f32 -> out [N][M] bf16 ----
__global__ __launch_bounds__(256) void wtrans_kernel(
    const float* __restrict__ in, u16* __restrict__ out, int M, int N)
{
  const int e = blockIdx.z;
  in  += (size_t)e * M * N;
  out += (size_t)e * M * N;
  const int r0 = blockIdx.y * 128;
  const int c0 = blockIdx.x * 64;
  __shared__ float tile[128][65];
  const int tid = threadIdx.x;
  const int lr = tid >> 4;
  const int lc = (tid & 15) * 4;
  #pragma unroll
  for (int p = 0; p < 8; p++) {
    int r = p * 16 + lr;
    float4 v = *(const float4*)(in + (size_t)(r0 + r) * N + (c0 + lc));
    tile[r][lc] = v.x; tile[r][lc + 1] = v.y; tile[r][lc + 2] = v.z; tile[r][lc + 3] = v.w;
  }
  __syncthreads();
  const int oc = tid >> 4;
  const int om = (tid & 15) * 8;
  #pragma unroll
  for (int p = 0; p < 4; p++) {
    int c = p * 16 + oc;
    short8 o;
    #pragma unroll
    for (int j = 0; j < 8; j++) o[j] = (short)f2bf(tile[om + j][c]);
    *(short8*)(out + (size_t)(c0 + c) * M + (r0 + om)) = o;
  }
}

// ============ 8-phase (4 phases/K-tile) grouped GEMM core macros ============
// 256x256 tile, BK=64, 8 waves (2Mx4N), dbuf 2x64KB LDS.
// Chunks of next tile: c0=A-half0, c1=B-half0, c2=B-half1, c3=A-half1 (2 loads each).
// Quadrant phases: q0=(0,0) q1=(0,1) q2=(1,1) q3=(1,0).
// vmcnt: 6,6,6,8 steady / 4,2,0,- tail (oldest-first drain, m135).

// ---------------- grouped GEMM1: H = gelu(Xg@W1 + b1) ----------------
__global__ __launch_bounds__(512, 2) void gemm1_kernel(
    const u16* __restrict__ Xg, const u16* __restrict__ W1T,
    const float* __restrict__ B1,
    const int* __restrict__ counts, const int* __restrict__ offsets,
    const int* __restrict__ map_e, const int* __restrict__ map_r,
    const int* __restrict__ nT, u16* __restrict__ H)
{
  __shared__ __align__(16) char lds[2 * 65536]; // buf: [A 32KB | B 32KB]
  const int gid   = xcd_swz(blockIdx.x, gridDim.x);
  const int n_idx = gid / MT256;
  const int t_idx = gid - n_idx * MT256;
  if (t_idx >= nT[0]) return;
  const int e    = map_e[t_idx];
  const int row0 = map_r[t_idx];
  const int cnt  = counts[e];
  const int off  = offsets[e];
  const int n0   = n_idx * 256;

  const int tid = threadIdx.x, wave = tid >> 6, lane = tid & 63;
  const int lr = lane & 15, lq = lane >> 4;
  const int wr = wave >> 2, wc = wave & 3;   // 2M x 4N
  const int l3 = lane >> 3, l7 = lane & 7;
  const int usrc = l7 ^ l3;

  // A staging calls c = (mh = c>>1, i = c&1): rows mh*64 + i*128 + wave*8 + l3
  // B staging calls c = (nh = c>>1, i = c&1): rows nh*32 + (i*2+(wave>>2))*64 + (wave&3)*8 + l3
  const char* gAc[4]; const char* gBc[4];
  int dA[4], dB[4];
  #pragma unroll
  for (int c = 0; c < 4; c++) {
    int rbA = (c >> 1) * 64 + (c & 1) * 128 + wave * 8;
    int sA  = imin(off + row0 + rbA + l3, NSLOT - 1);
    gAc[c] = (const char*)Xg + (size_t)sA * 2048 + usrc * 16;
    dA[c]  = rbA * 128 + lane * 16;
    int rbB = (c >> 1) * 32 + ((c & 1) * 2 + (wave >> 2)) * 64 + (wave & 3) * 8;
    gBc[c] = (const char*)W1T + (size_t)(e * FDIM + n0 + rbB + l3) * 2048 + usrc * 16;
    dB[c]  = 32768 + rbB * 128 + lane * 16;
  }

  f32x4 acc[8][4] = {};

  #define STAGE_A1(buf, mh, kB) { \
    gload16(gAc[(mh)*2]   + (kB), lds + (buf) * 65536 + dA[(mh)*2]);   \
    gload16(gAc[(mh)*2+1] + (kB), lds + (buf) * 65536 + dA[(mh)*2+1]); }
  #define STAGE_B1(buf, nh, kB) { \
    gload16(gBc[(nh)*2]   + (kB), lds + (buf) * 65536 + dB[(nh)*2]);   \
    gload16(gBc[(nh)*2+1] + (kB), lds + (buf) * 65536 + dB[(nh)*2+1]); }

  #define LOAD_A1(buf, mh) { \
    _Pragma("unroll") for (int ks = 0; ks < 2; ks++) { \
      int uu = ((ks * 4 + lq) ^ (lr & 7)) * 16; \
      _Pragma("unroll") for (int f = 0; f < 4; f++) \
        a[f][ks] = *(const short8*)(lds + (buf) * 65536 + (wr * 128 + (mh) * 64 + f * 16 + lr) * 128 + uu); } }
  #define LOAD_B1(buf, nh, bdst) { \
    _Pragma("unroll") for (int ks = 0; ks < 2; ks++) { \
      int uu = ((ks * 4 + lq) ^ (lr & 7)) * 16; \
      _Pragma("unroll") for (int g = 0; g < 2; g++) \
        bdst[g][ks] = *(const short8*)(lds + (buf) * 65536 + 32768 + (wc * 64 + (nh) * 32 + g * 16 + lr) * 128 + uu); } }

  #define MFMA16(mh, nh, bsrc) { \
    __builtin_amdgcn_s_setprio(1); \
    _Pragma("unroll") for (int f = 0; f < 4; f++) \
      _Pragma("unroll") for (int g = 0; g < 2; g++) \
        _Pragma("unroll") for (int ks = 0; ks < 2; ks++) \
          acc[(mh)*4+f][(nh)*2+g] = __builtin_amdgcn_mfma_f32_16x16x32_bf16(a[f][ks], bsrc[g][ks], acc[(mh)*4+f][(nh)*2+g], 0, 0, 0); \
    __builtin_amdgcn_s_setprio(0); }

  // prologue: all 4 chunks of tile 0
  STAGE_A1(0, 0, 0); STAGE_B1(0, 0, 0); STAGE_B1(0, 1, 0); STAGE_A1(0, 1, 0);

  const int NT = 16; // K=1024, BK=64
  #pragma unroll 1
  for (int t = 0; t < NT - 1; t++) {
    const int buf = t & 1, nb = buf ^ 1;
    const int kN = (t + 1) * 128;
    short8 a[4][2], b0[2][2], b1[2][2];
    // p0: q(0,0)
    STAGE_A1(nb, 0, kN); VM6; SCHED0; SBAR; SCHED0;
    LOAD_A1(buf, 0); LOAD_B1(buf, 0, b0);
    MFMA16(0, 0, b0); SCHED0; SBAR;
    // p1: q(0,1)
    STAGE_B1(nb, 0, kN); VM6; SCHED0; SBAR; SCHED0;
    LOAD_B1(buf, 1, b1);
    MFMA16(0, 1, b1); SCHED0; SBAR;
    // p2: q(1,1)
    STAGE_B1(nb, 1, kN); VM6; SCHED0; SBAR; SCHED0;
    LOAD_A1(buf, 1);
    MFMA16(1, 1, b1); SCHED0; SBAR;
    // p3: q(1,0)
    STAGE_A1(nb, 1, kN); VM8; SCHED0; SBAR; SCHED0;
    MFMA16(1, 0, b0); SCHED0; SBAR;
  }
  { // tail tile
    const int buf = (NT - 1) & 1;
    short8 a[4][2], b0[2][2], b1[2][2];
    VM4; SCHED0; SBAR; SCHED0;
    LOAD_A1(buf, 0); LOAD_B1(buf, 0, b0);
    MFMA16(0, 0, b0); SCHED0; SBAR;
    VM2; SCHED0; SBAR; SCHED0;
    LOAD_B1(buf, 1, b1);
    MFMA16(0, 1, b1); SCHED0; SBAR;
    VM0; SCHED0; SBAR; SCHED0;
    LOAD_A1(buf, 1);
    MFMA16(1, 1, b1); SCHED0; SBAR;
    MFMA16(1, 0, b0);
  }
  #undef STAGE_A1
  #undef STAGE_B1
  #undef LOAD_A1
  #undef LOAD_B1
  #undef MFMA16

  // epilogue: gelu + store bf16
  #pragma unroll
  for (int m = 0; m < 8; m++) {
    int rloc = wr * 128 + m * 16 + lq * 4;
    #pragma unroll
    for (int j = 0; j < 4; j++) {
      int r = rloc + j;
      if (row0 + r < cnt) {
        u16* Hrow = H + (size_t)(off + row0 + r) * FDIM;
        #pragma unroll
        for (int n = 0; n < 4; n++) {
          int col = n0 + wc * 64 + n * 16 + lr;
          float v = acc[m][n][j] + B1[e * FDIM + col];
          Hrow[col] = f2bf(gelu_fast(v));
        }
      }
    }
  }
}

// ---------------- grouped GEMM2 + fused combine ----------------
// Same 8-phase core; split-K=2 (NT=32 each); out[tok] += wgt*(H@W2 + b2).
__global__ __launch_bounds__(512, 2) void gemm2_kernel(
    const u16* __restrict__ H, const u16* __restrict__ W2T,
    const float* __restrict__ B2,
    const int* __restrict__ counts, const int* __restrict__ offsets,
    const int* __restrict__ slot_token, const float* __restrict__ slot_weight,
    const int* __restrict__ map_e, const int* __restrict__ map_r,
    const int* __restrict__ nT, float* __restrict__ out)
{
  __shared__ __align__(16) char lds[2 * 65536];
  const int gid   = xcd_swz(blockIdx.x, gridDim.x);
  const int sp    = gid / (4 * MT256);
  const int rem   = gid - sp * 4 * MT256;
  const int n_idx = rem / MT256;
  const int t_idx = rem - n_idx * MT256;
  if (t_idx >= nT[0]) return;
  const int e    = map_e[t_idx];
  const int row0 = map_r[t_idx];
  const int cnt  = counts[e];
  const int off  = offsets[e];
  const int n0   = n_idx * 256;
  const int kbase = sp * 4096;

  const int tid = threadIdx.x, wave = tid >> 6, lane = tid & 63;
  const int lr = lane & 15, lq = lane >> 4;
  const int wr = wave >> 2, wc = wave & 3;
  const int l3 = lane >> 3, l7 = lane & 7;
  const int usrc = l7 ^ l3;

  const char* gAc[4]; const char* gBc[4];
  int dA[4], dB[4];
  #pragma unroll
  for (int c = 0; c < 4; c++) {
    int rbA = (c >> 1) * 64 + (c & 1) * 128 + wave * 8;
    int sA  = imin(off + row0 + rbA + l3, NSLOT - 1);
    gAc[c] = (const char*)H + (size_t)sA * 8192 + kbase + usrc * 16;
    dA[c]  = rbA * 128 + lane * 16;
    int rbB = (c >> 1) * 32 + ((c & 1) * 2 + (wave >> 2)) * 64 + (wave & 3) * 8;
    gBc[c] = (const char*)W2T + (size_t)(e * DDIM + n0 + rbB + l3) * 8192 + kbase + usrc * 16;
    dB[c]  = 32768 + rbB * 128 + lane * 16;
  }

  f32x4 acc[8][4] = {};

  #define STAGE_A2(buf, mh, kB) { \
    gload16(gAc[(mh)*2]   + (kB), lds + (buf) * 65536 + dA[(mh)*2]);   \
    gload16(gAc[(mh)*2+1] + (kB), lds + (buf) * 65536 + dA[(mh)*2+1]); }
  #define STAGE_B2(buf, nh, kB) { \
    gload16(gBc[(nh)*2]   + (kB), lds + (buf) * 65536 + dB[(nh)*2]);   \
    gload16(gBc[(nh)*2+1] + (kB), lds + (buf) * 65536 + dB[(nh)*2+1]); }
  #define LOAD_A2(buf, mh) { \
    _Pragma("unroll") for (int ks = 0; ks < 2; ks++) { \
      int uu = ((ks * 4 + lq) ^ (lr & 7)) * 16; \
      _Pragma("unroll") for (int f = 0; f < 4; f++) \
        a[f][ks] = *(const short8*)(lds + (buf) * 65536 + (wr * 128 + (mh) * 64 + f * 16 + lr) * 128 + uu); } }
  #define LOAD_B2(buf, nh, bdst) { \
    _Pragma("unroll") for (int ks = 0; ks < 2; ks++) { \
      int uu = ((ks * 4 + lq) ^ (lr & 7)) * 16; \
      _Pragma("unroll") for (int g = 0; g < 2; g++) \
        bdst[g][ks] = *(const short8*)(lds + (buf) * 65536 + 32768 + (wc * 64 + (nh) * 32 + g * 16 + lr) * 128 + uu); } }
  #define MFMA16B(mh, nh, bsrc) { \
    __builtin_amdgcn_s_setprio(1); \
    _Pragma("unroll") for (int f = 0; f < 4; f++) \
      _Pragma("unroll") for (int g = 0; g < 2; g++) \
        _Pragma("unroll") for (int ks = 0; ks < 2; ks++) \
          acc[(mh)*4+f][(nh)*2+g] = __builtin_amdgcn_mfma_f32_16x16x32_bf16(a[f][ks], bsrc[g][ks], acc[(mh)*4+f][(nh)*2+g], 0, 0, 0); \
    __builtin_amdgcn_s_setprio(0); }

  STAGE_A2(0, 0, 0); STAGE_B2(0, 0, 0); STAGE_B2(0, 1, 0); STAGE_A2(0, 1, 0);

  const int NT = 32; // split K=2048, BK=64
  #pragma unroll 1
  for (int t = 0; t < NT - 1; t++) {
    const int buf = t & 1, nb = buf ^ 1;
    const int kN = (t + 1) * 128;
    short8 a[4][2], b0[2][2], b1[2][2];
    STAGE_A2(nb, 0, kN); VM6; SCHED0; SBAR; SCHED0;
    LOAD_A2(buf, 0); LOAD_B2(buf, 0, b0);
    MFMA16B(0, 0, b0); SCHED0; SBAR;
    STAGE_B2(nb, 0, kN); VM6; SCHED0; SBAR; SCHED0;
    LOAD_B2(buf, 1, b1);
    MFMA16B(0, 1, b1); SCHED0; SBAR;
    STAGE_B2(nb, 1, kN); VM6; SCHED0; SBAR; SCHED0;
    LOAD_A2(buf, 1);
    MFMA16B(1, 1, b1); SCHED0; SBAR;
    STAGE_A2(nb, 1, kN); VM8; SCHED0; SBAR; SCHED0;
    MFMA16B(1, 0, b0); SCHED0; SBAR;
  }
  {
    const int buf = (NT - 1) & 1;
    short8 a[4][2], b0[2][2], b1[2][2];
    VM4; SCHED0; SBAR; SCHED0;
    LOAD_A2(buf, 0); LOAD_B2(buf, 0, b0);
    MFMA16B(0, 0, b0); SCHED0; SBAR;
    VM2; SCHED0; SBAR; SCHED0;
    LOAD_B2(buf, 1, b1);
    MFMA16B(0, 1, b1); SCHED0; SBAR;
    VM0; SCHED0; SBAR; SCHED0;
    LOAD_A2(buf, 1);
    MFMA16B(1, 1, b1); SCHED0; SBAR;
    MFMA16B(1, 0, b0);
  }
  #undef STAGE_A2
  #undef STAGE_B2
  #undef LOAD_A2
  #undef LOAD_B2
  #undef MFMA16B

  #pragma unroll
  for (int m = 0; m < 8; m++) {
    int rloc = wr * 128 + m * 16 + lq * 4;
    #pragma unroll
    for (int j = 0; j < 4; j++) {
      int r = rloc + j;
      if (row0 + r >= cnt) continue;
      int s = off + row0 + r;
      int tok = slot_token[s];
      float wgt = slot_weight[s];
      #pragma unroll
      for (int n = 0; n < 4; n++) {
        int col = n0 + wc * 64 + n * 16 + lr;
        float v = acc[m][n][j];
        if (sp == 0) v += B2[e * DDIM + col];
        atomicAdd(&out[(size_t)tok * DDIM + col], wgt * v);
      }
    }
  }
}

extern "C" void kernel_launch(void* const* d_in, const int* in_sizes, int n_in,
                              void* d_out, int out_size, void* d_ws, size_t ws_size,
                              hipStream_t stream)
{
  (void)in_sizes; (void)n_in; (void)ws_size;
  const float* x  = (const float*)d_in[0];
  const float* gw = (const float*)d_in[1];
  const float* gb = (const float*)d_in[2];
  const float* w1 = (const float*)d_in[3];
  const float* b1 = (const float*)d_in[4];
  const float* w2 = (const float*)d_in[5];
  const float* b2 = (const float*)d_in[6];

  char* ws = (char*)d_ws;
  int*   counts = (int*)(ws + 0);
  int*   offp   = (int*)(ws + 64);
  int*   nT     = (int*)(ws + 128);
  int*   map_e  = (int*)(ws + 256);
  int*   map_r  = (int*)(ws + 1024);

  size_t p = 2048;
  int*   sel   = (int*)(ws + p);   p += (size_t)T_TOK * 2 * 4;
  float* wts   = (float*)(ws + p); p += (size_t)T_TOK * 2 * 4;
  int*   stok  = (int*)(ws + p);   p += (size_t)NSLOT * 4;
  float* swgt  = (float*)(ws + p); p += (size_t)NSLOT * 4;
  p = (p + 1048575) & ~(size_t)1048575;
  u16*   xb    = (u16*)(ws + p);   p += (size_t)T_TOK * DDIM * 2;
  u16*   Xg    = (u16*)(ws + p);   p += (size_t)NSLOT * DDIM * 2;
  u16*   w1t   = (u16*)(ws + p);   p += (size_t)NEXP * DDIM * FDIM * 2;
  u16*   w2t   = (u16*)(ws + p);   p += (size_t)NEXP * DDIM * FDIM * 2;
  u16*   Hbuf  = (u16*)(ws + p);

  hipMemsetAsync(ws, 0, 256, stream);
  hipMemsetAsync(d_out, 0, (size_t)out_size * sizeof(float), stream);
  router_kernel<<<T_TOK / 4, 256, 0, stream>>>(x, gw, gb, xb, counts, sel, wts);
  scan_assign_kernel<<<1, 256, 0, stream>>>(counts, sel, wts, offp, map_e, map_r, nT, stok, swgt);
  xgather_kernel<<<NSLOT / 2, 256, 0, stream>>>(xb, stok, Xg);
  wtrans_kernel<<<dim3(DDIM / 64, FDIM / 128, NEXP), 256, 0, stream>>>(w2, w2t, FDIM, DDIM);
  wtrans_kernel<<<dim3(FDIM / 64, DDIM / 128, NEXP), 256, 0, stream>>>(w1, w1t, DDIM, FDIM);

  gemm1_kernel<<<(FDIM / 256) * MT256, 512, 0, stream>>>(
      Xg, w1t, b1, counts, offp, map_e, map_r, nT, Hbuf);
  gemm2_kernel<<<2 * (DDIM / 256) * MT256, 512, 0, stream>>>(
      Hbuf, w2t, b2, counts, offp, stok, swgt, map_e, map_r, nT, (float*)d_out);
}